// Round 8
// baseline (452.662 us; speedup 1.0000x reference)
//
#include <hip/hip_runtime.h>
#include <hip/hip_bf16.h>
#include <hip/hip_cooperative_groups.h>

namespace cg = cooperative_groups;

typedef float f32x4 __attribute__((ext_vector_type(4)));
typedef short bf16x8 __attribute__((ext_vector_type(8)));
typedef unsigned short u16;

#define NTOK 768
#define DMOD 512
#define NH   16
#define DH   32
#define CZd  128
#define NN   (768*768)

static __device__ __forceinline__ u16 f2bf(float f) {
  __hip_bfloat16 h = __float2bfloat16(f);
  return __builtin_bit_cast(u16, h);
}
static __device__ __forceinline__ float bf2f(u16 u) {
  unsigned int x = ((unsigned int)u) << 16;
  return __builtin_bit_cast(float, x);
}

// ===========================================================================
// Shared device bodies (used by both the fused cooperative kernel and the
// fallback kernels) — all are the round-6 verified implementations.
// ===========================================================================

static __device__ __forceinline__ void unit_wcvt(
    int u, int t, const float* qw, const float* kw, const float* vw,
    const float* gw, const float* ow, u16* wbf, char* SM) {
  float (*tbuf)[33] = (float(*)[33])SM;
  int seg = u / 256, tile = u % 256;
  int k0 = (tile / 16) * 32, n0 = (tile % 16) * 32;
  const float* src = seg==0?qw: seg==1?kw: seg==2?vw: seg==3?gw: ow;
  u16* outw = wbf + (size_t)seg * (DMOD*DMOD);
  int tr  = t / 8, tc4 = (t % 8) * 4;
  float4 v = *(const float4*)(src + (size_t)(k0+tr)*DMOD + n0 + tc4);
  tbuf[tr][tc4+0]=v.x; tbuf[tr][tc4+1]=v.y; tbuf[tr][tc4+2]=v.z; tbuf[tr][tc4+3]=v.w;
  __syncthreads();
  int nr  = t / 8, kc4 = (t % 8) * 4;
  ushort4 o;
  o.x = f2bf(tbuf[kc4+0][nr]);
  o.y = f2bf(tbuf[kc4+1][nr]);
  o.z = f2bf(tbuf[kc4+2][nr]);
  o.w = f2bf(tbuf[kc4+3][nr]);
  *(ushort4*)(outw + (size_t)(n0+nr)*DMOD + k0 + kc4) = o;
}

static __device__ __forceinline__ void unit_lns(
    int u, int t, const float* s, const float* nsw, const float* nsb, u16* snb) {
  int i = u*4 + (t >> 6);
  int lane = t & 63;
  const float* row = s + (size_t)i*DMOD + lane*8;
  float4 a0 = *(const float4*)(row);
  float4 a1 = *(const float4*)(row + 4);
  float sum = a0.x+a0.y+a0.z+a0.w + a1.x+a1.y+a1.z+a1.w;
  float sq  = a0.x*a0.x+a0.y*a0.y+a0.z*a0.z+a0.w*a0.w
            + a1.x*a1.x+a1.y*a1.y+a1.z*a1.z+a1.w*a1.w;
  #pragma unroll
  for (int mk=1; mk<64; mk<<=1) { sum += __shfl_xor(sum,mk); sq += __shfl_xor(sq,mk); }
  float mu  = sum * (1.f/512.f);
  float var = sq  * (1.f/512.f) - mu*mu;
  float rs  = rsqrtf(var + 1e-5f);
  float4 w0 = *(const float4*)(nsw + lane*8);
  float4 w1 = *(const float4*)(nsw + lane*8 + 4);
  float4 b0 = *(const float4*)(nsb + lane*8);
  float4 b1 = *(const float4*)(nsb + lane*8 + 4);
  bf16x8 o;
  o[0]=(short)f2bf((a0.x-mu)*rs*w0.x+b0.x);
  o[1]=(short)f2bf((a0.y-mu)*rs*w0.y+b0.y);
  o[2]=(short)f2bf((a0.z-mu)*rs*w0.z+b0.z);
  o[3]=(short)f2bf((a0.w-mu)*rs*w0.w+b0.w);
  o[4]=(short)f2bf((a1.x-mu)*rs*w1.x+b1.x);
  o[5]=(short)f2bf((a1.y-mu)*rs*w1.y+b1.y);
  o[6]=(short)f2bf((a1.z-mu)*rs*w1.z+b1.z);
  o[7]=(short)f2bf((a1.w-mu)*rs*w1.w+b1.w);
  *(bf16x8*)(snb + (size_t)i*DMOD + lane*8) = o;
}

static __device__ __forceinline__ void unit_z(
    int u, int t, const float* z, const bf16x8* bfr, float4 w4, float4 b4,
    u16* biasb, char* SM) {
  u16* zt = (u16*)SM;          // 64 rows x pitch 136 bf16
  int lane = t & 63, wv = t >> 6;
  int c16 = lane & 15, c4 = lane >> 4;
  int rsub = t >> 5;           // 0..7
  int ch4  = (t & 31) * 4;     // 4 consecutive channels
  int i = u / 12, j0 = (u % 12) * 64;
  const float* ztile = z + ((size_t)i*NTOK + j0)*CZd;
  float4 xv[8];
  #pragma unroll
  for (int it=0; it<8; it++)
    xv[it] = *(const float4*)(ztile + (size_t)(it*8 + rsub)*CZd + ch4);
  float mu8[8], rs8[8];
  #pragma unroll
  for (int it=0; it<8; it++) {
    float4 v = xv[it];
    float sum = v.x+v.y+v.z+v.w;
    float sq  = v.x*v.x+v.y*v.y+v.z*v.z+v.w*v.w;
    #pragma unroll
    for (int mk=1; mk<32; mk<<=1) { sum += __shfl_xor(sum,mk); sq += __shfl_xor(sq,mk); }
    float mu = sum*(1.f/128.f);
    mu8[it] = mu;
    rs8[it] = rsqrtf(sq*(1.f/128.f) - mu*mu + 1e-5f);
  }
  #pragma unroll
  for (int it=0; it<8; it++) {
    float4 v = xv[it];
    float mu = mu8[it], rs = rs8[it];
    ushort4 o;
    o.x = f2bf((v.x-mu)*rs*w4.x + b4.x);
    o.y = f2bf((v.y-mu)*rs*w4.y + b4.y);
    o.z = f2bf((v.z-mu)*rs*w4.z + b4.z);
    o.w = f2bf((v.w-mu)*rs*w4.w + b4.w);
    *(ushort4*)(zt + (it*8 + rsub)*136 + ch4) = o;
  }
  __syncthreads();
  f32x4 acc = {0,0,0,0};
  #pragma unroll
  for (int ks=0; ks<4; ks++) {
    bf16x8 af = *(const bf16x8*)(zt + (wv*16 + c16)*136 + ks*32 + c4*8);
    acc = __builtin_amdgcn_mfma_f32_16x16x32_bf16(af, bfr[ks], acc, 0,0,0);
  }
  int jl = j0 + wv*16 + c4*4;
  u16* bp = biasb + ((size_t)i*NH + c16)*NTOK + jl;
  ushort4 st;
  st.x = f2bf(acc[0]); st.y = f2bf(acc[1]); st.z = f2bf(acc[2]); st.w = f2bf(acc[3]);
  *(ushort4*)bp = st;
}

static __device__ __forceinline__ void unit_qkvg(
    int u2, int t, const u16* snb, const u16* wbf, const float* qb,
    u16* qo, u16* ko, u16* vTo, float* go) {
  int lane = t & 63, wv = t >> 6;
  int c16 = lane & 15, c4 = lane >> 4;
  int mb = u2 % 24, nbx = u2 / 24;
  int wsel = nbx >> 3, n0 = (nbx & 7) * 64, m0 = mb * 32;
  const u16* wt = wbf + (size_t)wsel * (DMOD*DMOD);
  int wm = (wv >> 1) * 16, wn = (wv & 1) * 32;
  const u16* arow  = snb + (size_t)(m0 + wm + c16)*DMOD + c4*8;
  const u16* brow0 = wt + (size_t)(n0 + wn + c16)*DMOD + c4*8;
  const u16* brow1 = wt + (size_t)(n0 + wn + 16 + c16)*DMOD + c4*8;
  f32x4 acc0={0,0,0,0}, acc1={0,0,0,0};
  #pragma unroll 4
  for (int k0 = 0; k0 < DMOD; k0 += 32) {
    bf16x8 a  = *(const bf16x8*)(arow  + k0);
    bf16x8 b0 = *(const bf16x8*)(brow0 + k0);
    bf16x8 b1 = *(const bf16x8*)(brow1 + k0);
    acc0 = __builtin_amdgcn_mfma_f32_16x16x32_bf16(a,b0,acc0,0,0,0);
    acc1 = __builtin_amdgcn_mfma_f32_16x16x32_bf16(a,b1,acc1,0,0,0);
  }
  int r0 = c4*4;
  #pragma unroll
  for (int bn=0; bn<2; bn++) {
    f32x4 acc = bn==0?acc0:acc1;
    #pragma unroll
    for (int rr=0; rr<4; rr++) {
      int i = m0 + wm + r0 + rr;
      int n = n0 + wn + bn*16 + c16;
      float val = acc[rr];
      if (wsel == 0)      { val += qb[n]; qo[(size_t)i*DMOD + n] = f2bf(val); }
      else if (wsel == 1) { ko[(size_t)i*DMOD + n] = f2bf(val); }
      else if (wsel == 2) { vTo[(size_t)n*NTOK + i] = f2bf(val); }
      else                { go[(size_t)i*DMOD + n] = 1.f/(1.f + expf(-val)); }
    }
  }
}

static __device__ __forceinline__ void unit_attn(
    int u, int t, const u16* qo, const u16* ko, const u16* vTo,
    const u16* biasb, const float* go, u16* og, char* SM) {
  u16*   Pt  = (u16*)SM;                    // 4 x 16 x 72 bf16 = 9216 B
  float* OSp = (float*)(SM + 9216);         // 4 x 16 x 33 f32  = 8448 B
  float* LSp = (float*)(SM + 17664);        // 4 x 16 f32       = 256 B
  int lane = t & 63, wv = t >> 6;
  int c16 = lane & 15, c4 = lane >> 4;
  int h  = u & 15;
  int i0 = (u >> 4) * 16;
  int r0 = c4 * 4;
  bf16x8 qf = *(const bf16x8*)(qo + (size_t)(i0 + c16)*DMOD + h*DH + c4*8);
  f32x4 o0 = {0,0,0,0}, o1 = {0,0,0,0};
  float ls[4] = {0.f,0.f,0.f,0.f};
  const float scale = 0.17677669529663687f;  // 32^-0.5
  const u16* bbase = biasb + ((size_t)i0*NH + h)*NTOK;   // [i][h][j]
  u16* pt = Pt + wv*(16*72);
  for (int jj = 0; jj < 3; jj++) {
    int j0 = wv*192 + jj*64;
    bf16x8 kf0 = *(const bf16x8*)(ko + (size_t)(j0 +  0 + c16)*DMOD + h*DH + c4*8);
    bf16x8 kf1 = *(const bf16x8*)(ko + (size_t)(j0 + 16 + c16)*DMOD + h*DH + c4*8);
    bf16x8 kf2 = *(const bf16x8*)(ko + (size_t)(j0 + 32 + c16)*DMOD + h*DH + c4*8);
    bf16x8 kf3 = *(const bf16x8*)(ko + (size_t)(j0 + 48 + c16)*DMOD + h*DH + c4*8);
    f32x4 zz = {0,0,0,0};
    f32x4 s0 = __builtin_amdgcn_mfma_f32_16x16x32_bf16(qf,kf0,zz,0,0,0);
    f32x4 s1 = __builtin_amdgcn_mfma_f32_16x16x32_bf16(qf,kf1,zz,0,0,0);
    f32x4 s2 = __builtin_amdgcn_mfma_f32_16x16x32_bf16(qf,kf2,zz,0,0,0);
    f32x4 s3 = __builtin_amdgcn_mfma_f32_16x16x32_bf16(qf,kf3,zz,0,0,0);
    #pragma unroll
    for (int rr=0; rr<4; rr++) {
      const u16* bp = bbase + (size_t)(r0+rr)*(NH*NTOK) + j0 + c16;
      int row = (r0 + rr) * 72;
      float p0 = __expf(s0[rr]*scale + bf2f(bp[ 0]));
      float p1 = __expf(s1[rr]*scale + bf2f(bp[16]));
      float p2 = __expf(s2[rr]*scale + bf2f(bp[32]));
      float p3 = __expf(s3[rr]*scale + bf2f(bp[48]));
      ls[rr] += p0 + p1 + p2 + p3;
      pt[row + 0*16 + c16] = f2bf(p0);
      pt[row + 1*16 + c16] = f2bf(p1);
      pt[row + 2*16 + c16] = f2bf(p2);
      pt[row + 3*16 + c16] = f2bf(p3);
    }
    #pragma unroll
    for (int ks=0; ks<2; ks++) {
      bf16x8 pf = *(const bf16x8*)(pt + c16*72 + ks*32 + c4*8);
      bf16x8 v0 = *(const bf16x8*)(vTo + (size_t)(h*DH + c16)*NTOK      + j0 + ks*32 + c4*8);
      bf16x8 v1 = *(const bf16x8*)(vTo + (size_t)(h*DH + 16 + c16)*NTOK + j0 + ks*32 + c4*8);
      o0 = __builtin_amdgcn_mfma_f32_16x16x32_bf16(pf, v0, o0, 0,0,0);
      o1 = __builtin_amdgcn_mfma_f32_16x16x32_bf16(pf, v1, o1, 0,0,0);
    }
  }
  #pragma unroll
  for (int rr=0; rr<4; rr++) {
    float l = ls[rr];
    l += __shfl_xor(l,1); l += __shfl_xor(l,2); l += __shfl_xor(l,4); l += __shfl_xor(l,8);
    OSp[(wv*16 + r0+rr)*33 + c16]      = o0[rr];
    OSp[(wv*16 + r0+rr)*33 + 16 + c16] = o1[rr];
    if (c16 == 0) LSp[wv*16 + r0+rr] = l;
  }
  __syncthreads();
  #pragma unroll
  for (int uu=0; uu<2; uu++) {
    int idx = t + uu*256;
    int row = idx >> 5, d = idx & 31;
    float osum = OSp[(0*16+row)*33 + d] + OSp[(1*16+row)*33 + d]
               + OSp[(2*16+row)*33 + d] + OSp[(3*16+row)*33 + d];
    float lsum = LSp[0*16+row] + LSp[1*16+row] + LSp[2*16+row] + LSp[3*16+row];
    int i = i0 + row;
    float g = go[(size_t)i*DMOD + h*DH + d];
    og[(size_t)i*DMOD + h*DH + d] = f2bf(osum/lsum*g);
  }
}

static __device__ __forceinline__ void unit_out(
    int u, int t, const u16* og, const u16* owT, float* outp) {
  int lane = t & 63, wv = t >> 6;
  int c16 = lane & 15, c4 = lane >> 4;
  int mb = u % 24, nbx = u / 24;
  int m0 = mb*32, n0 = nbx*64;
  int wm = (wv >> 1) * 16, wn = (wv & 1) * 32;
  const u16* arow  = og  + (size_t)(m0 + wm + c16)*DMOD + c4*8;
  const u16* brow0 = owT + (size_t)(n0 + wn + c16)*DMOD + c4*8;
  const u16* brow1 = owT + (size_t)(n0 + wn + 16 + c16)*DMOD + c4*8;
  f32x4 acc0={0,0,0,0}, acc1={0,0,0,0};
  #pragma unroll 4
  for (int k0 = 0; k0 < DMOD; k0 += 32) {
    bf16x8 a  = *(const bf16x8*)(arow  + k0);
    bf16x8 b0 = *(const bf16x8*)(brow0 + k0);
    bf16x8 b1 = *(const bf16x8*)(brow1 + k0);
    acc0 = __builtin_amdgcn_mfma_f32_16x16x32_bf16(a,b0,acc0,0,0,0);
    acc1 = __builtin_amdgcn_mfma_f32_16x16x32_bf16(a,b1,acc1,0,0,0);
  }
  int r0 = c4*4;
  #pragma unroll
  for (int bn=0; bn<2; bn++) {
    f32x4 acc = bn==0?acc0:acc1;
    #pragma unroll
    for (int rr=0; rr<4; rr++)
      outp[(size_t)(m0 + wm + r0 + rr)*DMOD + n0 + wn + bn*16 + c16] = acc[rr];
  }
}

// ===========================================================================
// Fused cooperative kernel: 512 blocks (2/CU guaranteed), 4 phases.
// ===========================================================================
__global__ __launch_bounds__(256, 2) void fused_kernel(
    const float* __restrict__ s, const float* __restrict__ nsw, const float* __restrict__ nsb,
    const float* __restrict__ qw, const float* __restrict__ kw, const float* __restrict__ vw,
    const float* __restrict__ gw, const float* __restrict__ ow,
    const float* __restrict__ z, const float* __restrict__ znw, const float* __restrict__ znb,
    const float* __restrict__ zwp, const float* __restrict__ qb,
    u16* __restrict__ wbf, u16* __restrict__ snb, u16* __restrict__ biasb,
    u16* __restrict__ qo, u16* __restrict__ ko, u16* __restrict__ vTo,
    float* __restrict__ go, u16* __restrict__ og, float* __restrict__ outp) {
  cg::grid_group grid = cg::this_grid();
  __shared__ __align__(16) char SM[18432];
  int t = threadIdx.x;
  int bid0 = blockIdx.x;
  int NB = gridDim.x;          // 512
  int lane = t & 63;
  int c16 = lane & 15, c4 = lane >> 4;

  // ---- P0: weight cvt (1280) + LN(s) (192) ----
  for (int u = bid0; u < 1472; u += NB) {
    if (u < 1280) unit_wcvt(u, t, qw, kw, vw, gw, ow, wbf, SM);
    else          unit_lns(u - 1280, t, s, nsw, nsb, snb);
    __syncthreads();
  }
  __threadfence();
  grid.sync();

  // ---- P1: z stream (9216, first) + qkvg (768, last) ----
  {
    int ch4 = (t & 31) * 4;
    bf16x8 bfr[4];
    #pragma unroll
    for (int ks=0; ks<4; ks++) {
      #pragma unroll
      for (int jj=0; jj<8; jj++)
        bfr[ks][jj] = (short)f2bf(zwp[(ks*32 + c4*8 + jj)*16 + c16]);
    }
    float4 w4 = *(const float4*)(znw + ch4);
    float4 b4 = *(const float4*)(znb + ch4);
    for (int u = bid0; u < 9984; u += NB) {
      if (u < 9216) unit_z(u, t, z, bfr, w4, b4, biasb, SM);
      else          unit_qkvg(u - 9216, t, snb, wbf, qb, qo, ko, vTo, go);
      __syncthreads();
    }
  }
  __threadfence();
  grid.sync();

  // ---- P2: attention (768 units) ----
  for (int u = bid0; u < 768; u += NB) {
    unit_attn(u, t, qo, ko, vTo, biasb, go, og, SM);
    __syncthreads();
  }
  __threadfence();
  grid.sync();

  // ---- P3: out projection (192 units) ----
  for (int u = bid0; u < 192; u += NB)
    unit_out(u, t, og, wbf + (size_t)4*(DMOD*DMOD), outp);
}

// ===========================================================================
// Fallback kernels (round-6 verified structure)
// ===========================================================================
__global__ __launch_bounds__(256) void prep_kernel(
    const float* __restrict__ s, const float* __restrict__ nsw, const float* __restrict__ nsb,
    const float* __restrict__ qw, const float* __restrict__ kw, const float* __restrict__ vw,
    const float* __restrict__ gw, const float* __restrict__ ow,
    const float* __restrict__ z, const float* __restrict__ znw, const float* __restrict__ znb,
    const float* __restrict__ zwp,
    u16* __restrict__ wbf, u16* __restrict__ snb, u16* __restrict__ biasb) {
  __shared__ __align__(16) char SM[17408];
  int bid = blockIdx.x;
  int t = threadIdx.x;
  if (bid >= 9216) {
    if (bid < 10496) unit_wcvt(bid - 9216, t, qw, kw, vw, gw, ow, wbf, SM);
    else             unit_lns(bid - 10496, t, s, nsw, nsb, snb);
    return;
  }
  int lane = t & 63;
  int c16 = lane & 15, c4 = lane >> 4;
  int ch4 = (t & 31) * 4;
  bf16x8 bfr[4];
  #pragma unroll
  for (int ks=0; ks<4; ks++) {
    #pragma unroll
    for (int jj=0; jj<8; jj++)
      bfr[ks][jj] = (short)f2bf(zwp[(ks*32 + c4*8 + jj)*16 + c16]);
  }
  float4 w4 = *(const float4*)(znw + ch4);
  float4 b4 = *(const float4*)(znb + ch4);
  unit_z(bid, t, z, bfr, w4, b4, biasb, SM);
}

__global__ __launch_bounds__(256) void qkvg_kernel(
    const u16* __restrict__ sn, const u16* __restrict__ wts, const float* __restrict__ qb,
    u16* __restrict__ qo, u16* __restrict__ ko, u16* __restrict__ vTo, float* __restrict__ go) {
  unit_qkvg(blockIdx.x, threadIdx.x, sn, wts, qb, qo, ko, vTo, go);
}

__global__ __launch_bounds__(256) void attn_kernel(
    const u16* __restrict__ qm, const u16* __restrict__ km, const u16* __restrict__ vTm,
    const u16* __restrict__ bias, const float* __restrict__ gm, u16* __restrict__ og) {
  __shared__ __align__(16) char SM[17920];
  unit_attn(blockIdx.x, threadIdx.x, qm, km, vTm, bias, gm, og, SM);
}

__global__ __launch_bounds__(256) void out_kernel(
    const u16* __restrict__ og, const u16* __restrict__ owT, float* __restrict__ out) {
  unit_out(blockIdx.x, threadIdx.x, og, owT, out);
}

// ---------------------------------------------------------------------------
extern "C" void kernel_launch(void* const* d_in, const int* in_sizes, int n_in,
                              void* d_out, int out_size, void* d_ws, size_t ws_size,
                              hipStream_t stream) {
  const float* s   = (const float*)d_in[0];
  const float* z   = (const float*)d_in[1];
  const float* nsw = (const float*)d_in[2];
  const float* nsb = (const float*)d_in[3];
  const float* qw  = (const float*)d_in[4];
  const float* qb  = (const float*)d_in[5];
  const float* kw  = (const float*)d_in[6];
  const float* vw  = (const float*)d_in[7];
  const float* gw  = (const float*)d_in[8];
  const float* znw = (const float*)d_in[9];
  const float* znb = (const float*)d_in[10];
  const float* zw  = (const float*)d_in[11];
  const float* ow  = (const float*)d_in[12];
  float* out = (float*)d_out;

  char* p = (char*)d_ws;
  u16* w_bf    = (u16*)p;  p += (size_t)5*DMOD*DMOD*2;
  u16* sn_bf   = (u16*)p;  p += (size_t)NTOK*DMOD*2;
  u16* q_bf    = (u16*)p;  p += (size_t)NTOK*DMOD*2;
  u16* k_bf    = (u16*)p;  p += (size_t)NTOK*DMOD*2;
  u16* vT_bf   = (u16*)p;  p += (size_t)NTOK*DMOD*2;
  float* g_f   = (float*)p; p += (size_t)NTOK*DMOD*4;
  u16* og_bf   = (u16*)p;  p += (size_t)NTOK*DMOD*2;
  u16* bias_bf = (u16*)p;  p += (size_t)NH*NN*2;

  void* args[] = { (void*)&s, (void*)&nsw, (void*)&nsb, (void*)&qw, (void*)&kw,
                   (void*)&vw, (void*)&gw, (void*)&ow, (void*)&z, (void*)&znw,
                   (void*)&znb, (void*)&zw, (void*)&qb,
                   (void*)&w_bf, (void*)&sn_bf, (void*)&bias_bf,
                   (void*)&q_bf, (void*)&k_bf, (void*)&vT_bf, (void*)&g_f,
                   (void*)&og_bf, (void*)&out };
  hipError_t cerr = hipLaunchCooperativeKernel((void*)fused_kernel, dim3(512), dim3(256),
                                               args, 0, stream);
  if (cerr != hipSuccess) {
    (void)hipGetLastError();   // clear sticky error, take the 4-kernel path
    prep_kernel<<<dim3(10688), dim3(256), 0, stream>>>(
        s, nsw, nsb, qw, kw, vw, gw, ow, z, znw, znb, zw, w_bf, sn_bf, bias_bf);
    qkvg_kernel<<<dim3(768), dim3(256), 0, stream>>>(sn_bf, w_bf, qb, q_bf, k_bf, vT_bf, g_f);
    attn_kernel<<<dim3(768), dim3(256), 0, stream>>>(q_bf, k_bf, vT_bf, bias_bf, g_f, og_bf);
    out_kernel<<<dim3(192), dim3(256), 0, stream>>>(og_bf, w_bf + (size_t)4*DMOD*DMOD, out);
  }
}

// Round 9
// 440.602 us; speedup vs baseline: 1.0274x; 1.0274x over previous
//
#include <hip/hip_runtime.h>
#include <hip/hip_bf16.h>
#include <hip/hip_cooperative_groups.h>

namespace cg = cooperative_groups;

typedef float f32x4 __attribute__((ext_vector_type(4)));
typedef short bf16x8 __attribute__((ext_vector_type(8)));
typedef unsigned short u16;

#define NTOK 768
#define DMOD 512
#define NH   16
#define DH   32
#define CZd  128
#define NN   (768*768)

static __device__ __forceinline__ u16 f2bf(float f) {
  __hip_bfloat16 h = __float2bfloat16(f);
  return __builtin_bit_cast(u16, h);
}
static __device__ __forceinline__ float bf2f(u16 u) {
  unsigned int x = ((unsigned int)u) << 16;
  return __builtin_bit_cast(float, x);
}

// ===========================================================================
// z-unit as macros (NO function-boundary array passing -> registers, not
// scratch). Expansion context must provide: z, biasb, zt, rsub, ch4, wv, c16,
// c4, bfr[4], w4, b4.
// ===========================================================================
#define LOADZ(X, U) { \
  int zi_ = (U)/12, zj_ = ((U)%12)*64; \
  const float* zp_ = z + ((size_t)zi_*NTOK + zj_)*CZd; \
  _Pragma("unroll") \
  for (int it=0; it<8; it++) \
    X[it] = *(const float4*)(zp_ + (size_t)(it*8 + rsub)*CZd + ch4); \
}

#define PROCZ(X, U) { \
  float mu8_[8], rs8_[8]; \
  _Pragma("unroll") \
  for (int it=0; it<8; it++) { \
    float4 v_ = X[it]; \
    float sum_ = v_.x+v_.y+v_.z+v_.w; \
    float sq_  = v_.x*v_.x+v_.y*v_.y+v_.z*v_.z+v_.w*v_.w; \
    _Pragma("unroll") \
    for (int mk=1; mk<32; mk<<=1) { sum_ += __shfl_xor(sum_,mk); sq_ += __shfl_xor(sq_,mk); } \
    float mu_ = sum_*(1.f/128.f); \
    mu8_[it] = mu_; \
    rs8_[it] = rsqrtf(sq_*(1.f/128.f) - mu_*mu_ + 1e-5f); \
  } \
  _Pragma("unroll") \
  for (int it=0; it<8; it++) { \
    float4 v_ = X[it]; \
    float mu_ = mu8_[it], rs_ = rs8_[it]; \
    ushort4 o_; \
    o_.x = f2bf((v_.x-mu_)*rs_*w4.x + b4.x); \
    o_.y = f2bf((v_.y-mu_)*rs_*w4.y + b4.y); \
    o_.z = f2bf((v_.z-mu_)*rs_*w4.z + b4.z); \
    o_.w = f2bf((v_.w-mu_)*rs_*w4.w + b4.w); \
    *(ushort4*)(zt + (it*8 + rsub)*136 + ch4) = o_; \
  } \
  __syncthreads(); \
  f32x4 acc_ = {0,0,0,0}; \
  _Pragma("unroll") \
  for (int ks=0; ks<4; ks++) { \
    bf16x8 af_ = *(const bf16x8*)(zt + (wv*16 + c16)*136 + ks*32 + c4*8); \
    acc_ = __builtin_amdgcn_mfma_f32_16x16x32_bf16(af_, bfr[ks], acc_, 0,0,0); \
  } \
  { int zi_ = (U)/12, jl_ = ((U)%12)*64 + wv*16 + c4*4; \
    u16* bp_ = biasb + ((size_t)zi_*NH + c16)*NTOK + jl_; \
    ushort4 st_; \
    st_.x = f2bf(acc_[0]); st_.y = f2bf(acc_[1]); \
    st_.z = f2bf(acc_[2]); st_.w = f2bf(acc_[3]); \
    *(ushort4*)bp_ = st_; } \
  __syncthreads(); \
}

// ===========================================================================
// Simple unit bodies (no array-pointer params — safe as functions)
// ===========================================================================
static __device__ __forceinline__ void unit_wcvt(
    int u, int t, const float* qw, const float* kw, const float* vw,
    const float* gw, const float* ow, u16* wbf, char* SM) {
  float (*tbuf)[33] = (float(*)[33])SM;
  int seg = u / 256, tile = u % 256;
  int k0 = (tile / 16) * 32, n0 = (tile % 16) * 32;
  const float* src = seg==0?qw: seg==1?kw: seg==2?vw: seg==3?gw: ow;
  u16* outw = wbf + (size_t)seg * (DMOD*DMOD);
  int tr  = t / 8, tc4 = (t % 8) * 4;
  float4 v = *(const float4*)(src + (size_t)(k0+tr)*DMOD + n0 + tc4);
  tbuf[tr][tc4+0]=v.x; tbuf[tr][tc4+1]=v.y; tbuf[tr][tc4+2]=v.z; tbuf[tr][tc4+3]=v.w;
  __syncthreads();
  int nr  = t / 8, kc4 = (t % 8) * 4;
  ushort4 o;
  o.x = f2bf(tbuf[kc4+0][nr]);
  o.y = f2bf(tbuf[kc4+1][nr]);
  o.z = f2bf(tbuf[kc4+2][nr]);
  o.w = f2bf(tbuf[kc4+3][nr]);
  *(ushort4*)(outw + (size_t)(n0+nr)*DMOD + k0 + kc4) = o;
}

static __device__ __forceinline__ void unit_lns(
    int u, int t, const float* s, const float* nsw, const float* nsb, u16* snb) {
  int i = u*4 + (t >> 6);
  int lane = t & 63;
  const float* row = s + (size_t)i*DMOD + lane*8;
  float4 a0 = *(const float4*)(row);
  float4 a1 = *(const float4*)(row + 4);
  float sum = a0.x+a0.y+a0.z+a0.w + a1.x+a1.y+a1.z+a1.w;
  float sq  = a0.x*a0.x+a0.y*a0.y+a0.z*a0.z+a0.w*a0.w
            + a1.x*a1.x+a1.y*a1.y+a1.z*a1.z+a1.w*a1.w;
  #pragma unroll
  for (int mk=1; mk<64; mk<<=1) { sum += __shfl_xor(sum,mk); sq += __shfl_xor(sq,mk); }
  float mu  = sum * (1.f/512.f);
  float var = sq  * (1.f/512.f) - mu*mu;
  float rs  = rsqrtf(var + 1e-5f);
  float4 w0 = *(const float4*)(nsw + lane*8);
  float4 w1 = *(const float4*)(nsw + lane*8 + 4);
  float4 b0 = *(const float4*)(nsb + lane*8);
  float4 b1 = *(const float4*)(nsb + lane*8 + 4);
  bf16x8 o;
  o[0]=(short)f2bf((a0.x-mu)*rs*w0.x+b0.x);
  o[1]=(short)f2bf((a0.y-mu)*rs*w0.y+b0.y);
  o[2]=(short)f2bf((a0.z-mu)*rs*w0.z+b0.z);
  o[3]=(short)f2bf((a0.w-mu)*rs*w0.w+b0.w);
  o[4]=(short)f2bf((a1.x-mu)*rs*w1.x+b1.x);
  o[5]=(short)f2bf((a1.y-mu)*rs*w1.y+b1.y);
  o[6]=(short)f2bf((a1.z-mu)*rs*w1.z+b1.z);
  o[7]=(short)f2bf((a1.w-mu)*rs*w1.w+b1.w);
  *(bf16x8*)(snb + (size_t)i*DMOD + lane*8) = o;
}

static __device__ __forceinline__ void unit_qkvg(
    int u2, int t, const u16* snb, const u16* wbf, const float* qb,
    u16* qo, u16* ko, u16* vTo, float* go) {
  int lane = t & 63, wv = t >> 6;
  int c16 = lane & 15, c4 = lane >> 4;
  int mb = u2 % 24, nbx = u2 / 24;
  int wsel = nbx >> 3, n0 = (nbx & 7) * 64, m0 = mb * 32;
  const u16* wt = wbf + (size_t)wsel * (DMOD*DMOD);
  int wm = (wv >> 1) * 16, wn = (wv & 1) * 32;
  const u16* arow  = snb + (size_t)(m0 + wm + c16)*DMOD + c4*8;
  const u16* brow0 = wt + (size_t)(n0 + wn + c16)*DMOD + c4*8;
  const u16* brow1 = wt + (size_t)(n0 + wn + 16 + c16)*DMOD + c4*8;
  f32x4 acc0={0,0,0,0}, acc1={0,0,0,0};
  #pragma unroll 4
  for (int k0 = 0; k0 < DMOD; k0 += 32) {
    bf16x8 a  = *(const bf16x8*)(arow  + k0);
    bf16x8 b0 = *(const bf16x8*)(brow0 + k0);
    bf16x8 b1 = *(const bf16x8*)(brow1 + k0);
    acc0 = __builtin_amdgcn_mfma_f32_16x16x32_bf16(a,b0,acc0,0,0,0);
    acc1 = __builtin_amdgcn_mfma_f32_16x16x32_bf16(a,b1,acc1,0,0,0);
  }
  int r0 = c4*4;
  #pragma unroll
  for (int bn=0; bn<2; bn++) {
    f32x4 acc = bn==0?acc0:acc1;
    #pragma unroll
    for (int rr=0; rr<4; rr++) {
      int i = m0 + wm + r0 + rr;
      int n = n0 + wn + bn*16 + c16;
      float val = acc[rr];
      if (wsel == 0)      { val += qb[n]; qo[(size_t)i*DMOD + n] = f2bf(val); }
      else if (wsel == 1) { ko[(size_t)i*DMOD + n] = f2bf(val); }
      else if (wsel == 2) { vTo[(size_t)n*NTOK + i] = f2bf(val); }
      else                { go[(size_t)i*DMOD + n] = 1.f/(1.f + expf(-val)); }
    }
  }
}

static __device__ __forceinline__ void unit_attn(
    int u, int t, const u16* qo, const u16* ko, const u16* vTo,
    const u16* biasb, const float* go, u16* og, char* SM) {
  u16*   Pt  = (u16*)SM;
  float* OSp = (float*)(SM + 9216);
  float* LSp = (float*)(SM + 17664);
  int lane = t & 63, wv = t >> 6;
  int c16 = lane & 15, c4 = lane >> 4;
  int h  = u & 15;
  int i0 = (u >> 4) * 16;
  int r0 = c4 * 4;
  bf16x8 qf = *(const bf16x8*)(qo + (size_t)(i0 + c16)*DMOD + h*DH + c4*8);
  f32x4 o0 = {0,0,0,0}, o1 = {0,0,0,0};
  float ls[4] = {0.f,0.f,0.f,0.f};
  const float scale = 0.17677669529663687f;
  const u16* bbase = biasb + ((size_t)i0*NH + h)*NTOK;
  u16* pt = Pt + wv*(16*72);
  for (int jj = 0; jj < 3; jj++) {
    int j0 = wv*192 + jj*64;
    bf16x8 kf0 = *(const bf16x8*)(ko + (size_t)(j0 +  0 + c16)*DMOD + h*DH + c4*8);
    bf16x8 kf1 = *(const bf16x8*)(ko + (size_t)(j0 + 16 + c16)*DMOD + h*DH + c4*8);
    bf16x8 kf2 = *(const bf16x8*)(ko + (size_t)(j0 + 32 + c16)*DMOD + h*DH + c4*8);
    bf16x8 kf3 = *(const bf16x8*)(ko + (size_t)(j0 + 48 + c16)*DMOD + h*DH + c4*8);
    f32x4 zz = {0,0,0,0};
    f32x4 s0 = __builtin_amdgcn_mfma_f32_16x16x32_bf16(qf,kf0,zz,0,0,0);
    f32x4 s1 = __builtin_amdgcn_mfma_f32_16x16x32_bf16(qf,kf1,zz,0,0,0);
    f32x4 s2 = __builtin_amdgcn_mfma_f32_16x16x32_bf16(qf,kf2,zz,0,0,0);
    f32x4 s3 = __builtin_amdgcn_mfma_f32_16x16x32_bf16(qf,kf3,zz,0,0,0);
    #pragma unroll
    for (int rr=0; rr<4; rr++) {
      const u16* bp = bbase + (size_t)(r0+rr)*(NH*NTOK) + j0 + c16;
      int row = (r0 + rr) * 72;
      float p0 = __expf(s0[rr]*scale + bf2f(bp[ 0]));
      float p1 = __expf(s1[rr]*scale + bf2f(bp[16]));
      float p2 = __expf(s2[rr]*scale + bf2f(bp[32]));
      float p3 = __expf(s3[rr]*scale + bf2f(bp[48]));
      ls[rr] += p0 + p1 + p2 + p3;
      pt[row + 0*16 + c16] = f2bf(p0);
      pt[row + 1*16 + c16] = f2bf(p1);
      pt[row + 2*16 + c16] = f2bf(p2);
      pt[row + 3*16 + c16] = f2bf(p3);
    }
    #pragma unroll
    for (int ks=0; ks<2; ks++) {
      bf16x8 pf = *(const bf16x8*)(pt + c16*72 + ks*32 + c4*8);
      bf16x8 v0 = *(const bf16x8*)(vTo + (size_t)(h*DH + c16)*NTOK      + j0 + ks*32 + c4*8);
      bf16x8 v1 = *(const bf16x8*)(vTo + (size_t)(h*DH + 16 + c16)*NTOK + j0 + ks*32 + c4*8);
      o0 = __builtin_amdgcn_mfma_f32_16x16x32_bf16(pf, v0, o0, 0,0,0);
      o1 = __builtin_amdgcn_mfma_f32_16x16x32_bf16(pf, v1, o1, 0,0,0);
    }
  }
  #pragma unroll
  for (int rr=0; rr<4; rr++) {
    float l = ls[rr];
    l += __shfl_xor(l,1); l += __shfl_xor(l,2); l += __shfl_xor(l,4); l += __shfl_xor(l,8);
    OSp[(wv*16 + r0+rr)*33 + c16]      = o0[rr];
    OSp[(wv*16 + r0+rr)*33 + 16 + c16] = o1[rr];
    if (c16 == 0) LSp[wv*16 + r0+rr] = l;
  }
  __syncthreads();
  #pragma unroll
  for (int uu=0; uu<2; uu++) {
    int idx = t + uu*256;
    int row = idx >> 5, d = idx & 31;
    float osum = OSp[(0*16+row)*33 + d] + OSp[(1*16+row)*33 + d]
               + OSp[(2*16+row)*33 + d] + OSp[(3*16+row)*33 + d];
    float lsum = LSp[0*16+row] + LSp[1*16+row] + LSp[2*16+row] + LSp[3*16+row];
    int i = i0 + row;
    float g = go[(size_t)i*DMOD + h*DH + d];
    og[(size_t)i*DMOD + h*DH + d] = f2bf(osum/lsum*g);
  }
}

static __device__ __forceinline__ void unit_out(
    int u, int t, const u16* og, const u16* owT, float* outp) {
  int lane = t & 63, wv = t >> 6;
  int c16 = lane & 15, c4 = lane >> 4;
  int mb = u % 24, nbx = u / 24;
  int m0 = mb*32, n0 = nbx*64;
  int wm = (wv >> 1) * 16, wn = (wv & 1) * 32;
  const u16* arow  = og  + (size_t)(m0 + wm + c16)*DMOD + c4*8;
  const u16* brow0 = owT + (size_t)(n0 + wn + c16)*DMOD + c4*8;
  const u16* brow1 = owT + (size_t)(n0 + wn + 16 + c16)*DMOD + c4*8;
  f32x4 acc0={0,0,0,0}, acc1={0,0,0,0};
  #pragma unroll 4
  for (int k0 = 0; k0 < DMOD; k0 += 32) {
    bf16x8 a  = *(const bf16x8*)(arow  + k0);
    bf16x8 b0 = *(const bf16x8*)(brow0 + k0);
    bf16x8 b1 = *(const bf16x8*)(brow1 + k0);
    acc0 = __builtin_amdgcn_mfma_f32_16x16x32_bf16(a,b0,acc0,0,0,0);
    acc1 = __builtin_amdgcn_mfma_f32_16x16x32_bf16(a,b1,acc1,0,0,0);
  }
  int r0 = c4*4;
  #pragma unroll
  for (int bn=0; bn<2; bn++) {
    f32x4 acc = bn==0?acc0:acc1;
    #pragma unroll
    for (int rr=0; rr<4; rr++)
      outp[(size_t)(m0 + wm + r0 + rr)*DMOD + n0 + wn + bn*16 + c16] = acc[rr];
  }
}

// ===========================================================================
// Fused cooperative kernel: 512 blocks, z-units register-double-buffered.
// ===========================================================================
__global__ __launch_bounds__(256, 2) void fused_kernel(
    const float* __restrict__ s, const float* __restrict__ nsw, const float* __restrict__ nsb,
    const float* __restrict__ qw, const float* __restrict__ kw, const float* __restrict__ vw,
    const float* __restrict__ gw, const float* __restrict__ ow,
    const float* __restrict__ z, const float* __restrict__ znw, const float* __restrict__ znb,
    const float* __restrict__ zwp, const float* __restrict__ qb,
    u16* __restrict__ wbf, u16* __restrict__ snb, u16* __restrict__ biasb,
    u16* __restrict__ qo, u16* __restrict__ ko, u16* __restrict__ vTo,
    float* __restrict__ go, u16* __restrict__ og, float* __restrict__ outp) {
  cg::grid_group grid = cg::this_grid();
  __shared__ __align__(16) char SM[18432];
  int t = threadIdx.x;
  int bid0 = blockIdx.x;
  const int NB = 512;
  int lane = t & 63, wv = t >> 6;
  int c16 = lane & 15, c4 = lane >> 4;

  // ---- P0: weight cvt (1280) + LN(s) (192) ----
  for (int u = bid0; u < 1472; u += NB) {
    if (u < 1280) unit_wcvt(u, t, qw, kw, vw, gw, ow, wbf, SM);
    else          unit_lns(u - 1280, t, s, nsw, nsb, snb);
    __syncthreads();
  }
  __threadfence();
  grid.sync();

  // ---- P1: z stream (18 units/block, prefetched) + qkvg tail ----
  {
    u16* zt = (u16*)SM;
    int rsub = t >> 5;
    int ch4  = (t & 31) * 4;
    bf16x8 bfr[4];
    #pragma unroll
    for (int ks=0; ks<4; ks++) {
      #pragma unroll
      for (int jj=0; jj<8; jj++)
        bfr[ks][jj] = (short)f2bf(zwp[(ks*32 + c4*8 + jj)*16 + c16]);
    }
    float4 w4 = *(const float4*)(znw + ch4);
    float4 b4 = *(const float4*)(znb + ch4);
    float4 xa[8], xb[8];
    int u0 = bid0;
    LOADZ(xa, u0)
    #pragma unroll 1
    for (int kk = 0; kk < 9; kk++) {
      int u1 = u0 + NB;
      LOADZ(xb, u1)
      PROCZ(xa, u0)
      if (kk < 8) { int u2 = u0 + 2*NB; LOADZ(xa, u2) }
      PROCZ(xb, u1)
      u0 += 2*NB;
    }
    for (int u = bid0 + 18*NB; u < 9984; u += NB)
      unit_qkvg(u - 9216, t, snb, wbf, qb, qo, ko, vTo, go);
  }
  __threadfence();
  grid.sync();

  // ---- P2: attention (768 units) ----
  for (int u = bid0; u < 768; u += NB) {
    unit_attn(u, t, qo, ko, vTo, biasb, go, og, SM);
    __syncthreads();
  }
  __threadfence();
  grid.sync();

  // ---- P3: out projection (192 units) ----
  for (int u = bid0; u < 192; u += NB)
    unit_out(u, t, og, wbf + (size_t)4*(DMOD*DMOD), outp);
}

// ===========================================================================
// Fallback kernels (round-6 verified structure; z body via same macros)
// ===========================================================================
__global__ __launch_bounds__(256) void prep_kernel(
    const float* __restrict__ s, const float* __restrict__ nsw, const float* __restrict__ nsb,
    const float* __restrict__ qw, const float* __restrict__ kw, const float* __restrict__ vw,
    const float* __restrict__ gw, const float* __restrict__ ow,
    const float* __restrict__ z, const float* __restrict__ znw, const float* __restrict__ znb,
    const float* __restrict__ zwp,
    u16* __restrict__ wbf, u16* __restrict__ snb, u16* __restrict__ biasb) {
  __shared__ __align__(16) char SM[17408];
  int bid = blockIdx.x;
  int t = threadIdx.x;
  if (bid >= 9216) {
    if (bid < 10496) unit_wcvt(bid - 9216, t, qw, kw, vw, gw, ow, wbf, SM);
    else             unit_lns(bid - 10496, t, s, nsw, nsb, snb);
    return;
  }
  u16* zt = (u16*)SM;
  int lane = t & 63, wv = t >> 6;
  int c16 = lane & 15, c4 = lane >> 4;
  int rsub = t >> 5;
  int ch4  = (t & 31) * 4;
  bf16x8 bfr[4];
  #pragma unroll
  for (int ks=0; ks<4; ks++) {
    #pragma unroll
    for (int jj=0; jj<8; jj++)
      bfr[ks][jj] = (short)f2bf(zwp[(ks*32 + c4*8 + jj)*16 + c16]);
  }
  float4 w4 = *(const float4*)(znw + ch4);
  float4 b4 = *(const float4*)(znb + ch4);
  float4 xa[8];
  LOADZ(xa, bid)
  PROCZ(xa, bid)
}

__global__ __launch_bounds__(256) void qkvg_kernel(
    const u16* __restrict__ sn, const u16* __restrict__ wts, const float* __restrict__ qb,
    u16* __restrict__ qo, u16* __restrict__ ko, u16* __restrict__ vTo, float* __restrict__ go) {
  unit_qkvg(blockIdx.x, threadIdx.x, sn, wts, qb, qo, ko, vTo, go);
}

__global__ __launch_bounds__(256) void attn_kernel(
    const u16* __restrict__ qm, const u16* __restrict__ km, const u16* __restrict__ vTm,
    const u16* __restrict__ bias, const float* __restrict__ gm, u16* __restrict__ og) {
  __shared__ __align__(16) char SM[17920];
  unit_attn(blockIdx.x, threadIdx.x, qm, km, vTm, bias, gm, og, SM);
}

__global__ __launch_bounds__(256) void out_kernel(
    const u16* __restrict__ og, const u16* __restrict__ owT, float* __restrict__ out) {
  unit_out(blockIdx.x, threadIdx.x, og, owT, out);
}

// ---------------------------------------------------------------------------
extern "C" void kernel_launch(void* const* d_in, const int* in_sizes, int n_in,
                              void* d_out, int out_size, void* d_ws, size_t ws_size,
                              hipStream_t stream) {
  const float* s   = (const float*)d_in[0];
  const float* z   = (const float*)d_in[1];
  const float* nsw = (const float*)d_in[2];
  const float* nsb = (const float*)d_in[3];
  const float* qw  = (const float*)d_in[4];
  const float* qb  = (const float*)d_in[5];
  const float* kw  = (const float*)d_in[6];
  const float* vw  = (const float*)d_in[7];
  const float* gw  = (const float*)d_in[8];
  const float* znw = (const float*)d_in[9];
  const float* znb = (const float*)d_in[10];
  const float* zw  = (const float*)d_in[11];
  const float* ow  = (const float*)d_in[12];
  float* out = (float*)d_out;

  char* p = (char*)d_ws;
  u16* w_bf    = (u16*)p;  p += (size_t)5*DMOD*DMOD*2;
  u16* sn_bf   = (u16*)p;  p += (size_t)NTOK*DMOD*2;
  u16* q_bf    = (u16*)p;  p += (size_t)NTOK*DMOD*2;
  u16* k_bf    = (u16*)p;  p += (size_t)NTOK*DMOD*2;
  u16* vT_bf   = (u16*)p;  p += (size_t)NTOK*DMOD*2;
  float* g_f   = (float*)p; p += (size_t)NTOK*DMOD*4;
  u16* og_bf   = (u16*)p;  p += (size_t)NTOK*DMOD*2;
  u16* bias_bf = (u16*)p;  p += (size_t)NH*NN*2;

  void* args[] = { (void*)&s, (void*)&nsw, (void*)&nsb, (void*)&qw, (void*)&kw,
                   (void*)&vw, (void*)&gw, (void*)&ow, (void*)&z, (void*)&znw,
                   (void*)&znb, (void*)&zw, (void*)&qb,
                   (void*)&w_bf, (void*)&sn_bf, (void*)&bias_bf,
                   (void*)&q_bf, (void*)&k_bf, (void*)&vT_bf, (void*)&g_f,
                   (void*)&og_bf, (void*)&out };
  hipError_t cerr = hipLaunchCooperativeKernel((void*)fused_kernel, dim3(512), dim3(256),
                                               args, 0, stream);
  if (cerr != hipSuccess) {
    (void)hipGetLastError();   // clear sticky error, take the 4-kernel path
    prep_kernel<<<dim3(10688), dim3(256), 0, stream>>>(
        s, nsw, nsb, qw, kw, vw, gw, ow, z, znw, znb, zw, w_bf, sn_bf, bias_bf);
    qkvg_kernel<<<dim3(768), dim3(256), 0, stream>>>(sn_bf, w_bf, qb, q_bf, k_bf, vT_bf, g_f);
    attn_kernel<<<dim3(768), dim3(256), 0, stream>>>(q_bf, k_bf, vT_bf, bias_bf, g_f, og_bf);
    out_kernel<<<dim3(192), dim3(256), 0, stream>>>(og_bf, w_bf + (size_t)4*DMOD*DMOD, out);
  }
}

// Round 10
// 437.407 us; speedup vs baseline: 1.0349x; 1.0073x over previous
//
#include <hip/hip_runtime.h>
#include <hip/hip_bf16.h>
#include <hip/hip_cooperative_groups.h>

namespace cg = cooperative_groups;

typedef float f32x4 __attribute__((ext_vector_type(4)));
typedef short bf16x8 __attribute__((ext_vector_type(8)));
typedef unsigned short u16;

#define NTOK 768
#define DMOD 512
#define NH   16
#define DH   32
#define CZd  128
#define NN   (768*768)

static __device__ __forceinline__ u16 f2bf(float f) {
  __hip_bfloat16 h = __float2bfloat16(f);
  return __builtin_bit_cast(u16, h);
}
static __device__ __forceinline__ float bf2f(u16 u) {
  unsigned int x = ((unsigned int)u) << 16;
  return __builtin_bit_cast(float, x);
}

// ===========================================================================
// z-unit as macros (no function-boundary array passing). Context must
// provide: z, biasb, zt, rsub, ch4, wv, c16, c4, bfr[4], w4, b4.
// ===========================================================================
#define LOADZ(X, U) { \
  int zi_ = (U)/12, zj_ = ((U)%12)*64; \
  const float* zp_ = z + ((size_t)zi_*NTOK + zj_)*CZd; \
  _Pragma("unroll") \
  for (int it=0; it<8; it++) \
    X[it] = *(const float4*)(zp_ + (size_t)(it*8 + rsub)*CZd + ch4); \
}

#define PROCZ(X, U) { \
  float mu8_[8], rs8_[8]; \
  _Pragma("unroll") \
  for (int it=0; it<8; it++) { \
    float4 v_ = X[it]; \
    float sum_ = v_.x+v_.y+v_.z+v_.w; \
    float sq_  = v_.x*v_.x+v_.y*v_.y+v_.z*v_.z+v_.w*v_.w; \
    _Pragma("unroll") \
    for (int mk=1; mk<32; mk<<=1) { sum_ += __shfl_xor(sum_,mk); sq_ += __shfl_xor(sq_,mk); } \
    float mu_ = sum_*(1.f/128.f); \
    mu8_[it] = mu_; \
    rs8_[it] = rsqrtf(sq_*(1.f/128.f) - mu_*mu_ + 1e-5f); \
  } \
  _Pragma("unroll") \
  for (int it=0; it<8; it++) { \
    float4 v_ = X[it]; \
    float mu_ = mu8_[it], rs_ = rs8_[it]; \
    ushort4 o_; \
    o_.x = f2bf((v_.x-mu_)*rs_*w4.x + b4.x); \
    o_.y = f2bf((v_.y-mu_)*rs_*w4.y + b4.y); \
    o_.z = f2bf((v_.z-mu_)*rs_*w4.z + b4.z); \
    o_.w = f2bf((v_.w-mu_)*rs_*w4.w + b4.w); \
    *(ushort4*)(zt + (it*8 + rsub)*136 + ch4) = o_; \
  } \
  __syncthreads(); \
  f32x4 acc_ = {0,0,0,0}; \
  _Pragma("unroll") \
  for (int ks=0; ks<4; ks++) { \
    bf16x8 af_ = *(const bf16x8*)(zt + (wv*16 + c16)*136 + ks*32 + c4*8); \
    acc_ = __builtin_amdgcn_mfma_f32_16x16x32_bf16(af_, bfr[ks], acc_, 0,0,0); \
  } \
  { int zi_ = (U)/12, jl_ = ((U)%12)*64 + wv*16 + c4*4; \
    u16* bp_ = biasb + ((size_t)zi_*NH + c16)*NTOK + jl_; \
    ushort4 st_; \
    st_.x = f2bf(acc_[0]); st_.y = f2bf(acc_[1]); \
    st_.z = f2bf(acc_[2]); st_.w = f2bf(acc_[3]); \
    *(ushort4*)bp_ = st_; } \
  __syncthreads(); \
}

// ===========================================================================
// Simple unit bodies
// ===========================================================================
static __device__ __forceinline__ void unit_wcvt(
    int u, int t, const float* qw, const float* kw, const float* vw,
    const float* gw, const float* ow, u16* wbf, char* SM) {
  float (*tbuf)[33] = (float(*)[33])SM;
  int seg = u / 256, tile = u % 256;
  int k0 = (tile / 16) * 32, n0 = (tile % 16) * 32;
  const float* src = seg==0?qw: seg==1?kw: seg==2?vw: seg==3?gw: ow;
  u16* outw = wbf + (size_t)seg * (DMOD*DMOD);
  int tr  = t / 8, tc4 = (t % 8) * 4;
  float4 v = *(const float4*)(src + (size_t)(k0+tr)*DMOD + n0 + tc4);
  tbuf[tr][tc4+0]=v.x; tbuf[tr][tc4+1]=v.y; tbuf[tr][tc4+2]=v.z; tbuf[tr][tc4+3]=v.w;
  __syncthreads();
  int nr  = t / 8, kc4 = (t % 8) * 4;
  ushort4 o;
  o.x = f2bf(tbuf[kc4+0][nr]);
  o.y = f2bf(tbuf[kc4+1][nr]);
  o.z = f2bf(tbuf[kc4+2][nr]);
  o.w = f2bf(tbuf[kc4+3][nr]);
  *(ushort4*)(outw + (size_t)(n0+nr)*DMOD + k0 + kc4) = o;
}

static __device__ __forceinline__ void unit_lns(
    int u, int t, const float* s, const float* nsw, const float* nsb, u16* snb) {
  int i = u*4 + (t >> 6);
  int lane = t & 63;
  const float* row = s + (size_t)i*DMOD + lane*8;
  float4 a0 = *(const float4*)(row);
  float4 a1 = *(const float4*)(row + 4);
  float sum = a0.x+a0.y+a0.z+a0.w + a1.x+a1.y+a1.z+a1.w;
  float sq  = a0.x*a0.x+a0.y*a0.y+a0.z*a0.z+a0.w*a0.w
            + a1.x*a1.x+a1.y*a1.y+a1.z*a1.z+a1.w*a1.w;
  #pragma unroll
  for (int mk=1; mk<64; mk<<=1) { sum += __shfl_xor(sum,mk); sq += __shfl_xor(sq,mk); }
  float mu  = sum * (1.f/512.f);
  float var = sq  * (1.f/512.f) - mu*mu;
  float rs  = rsqrtf(var + 1e-5f);
  float4 w0 = *(const float4*)(nsw + lane*8);
  float4 w1 = *(const float4*)(nsw + lane*8 + 4);
  float4 b0 = *(const float4*)(nsb + lane*8);
  float4 b1 = *(const float4*)(nsb + lane*8 + 4);
  bf16x8 o;
  o[0]=(short)f2bf((a0.x-mu)*rs*w0.x+b0.x);
  o[1]=(short)f2bf((a0.y-mu)*rs*w0.y+b0.y);
  o[2]=(short)f2bf((a0.z-mu)*rs*w0.z+b0.z);
  o[3]=(short)f2bf((a0.w-mu)*rs*w0.w+b0.w);
  o[4]=(short)f2bf((a1.x-mu)*rs*w1.x+b1.x);
  o[5]=(short)f2bf((a1.y-mu)*rs*w1.y+b1.y);
  o[6]=(short)f2bf((a1.z-mu)*rs*w1.z+b1.z);
  o[7]=(short)f2bf((a1.w-mu)*rs*w1.w+b1.w);
  *(bf16x8*)(snb + (size_t)i*DMOD + lane*8) = o;
}

static __device__ __forceinline__ void unit_qkvg(
    int u2, int t, const u16* snb, const u16* wbf, const float* qb,
    u16* qo, u16* ko, u16* vTo, float* go) {
  int lane = t & 63, wv = t >> 6;
  int c16 = lane & 15, c4 = lane >> 4;
  int mb = u2 % 24, nbx = u2 / 24;
  int wsel = nbx >> 3, n0 = (nbx & 7) * 64, m0 = mb * 32;
  const u16* wt = wbf + (size_t)wsel * (DMOD*DMOD);
  int wm = (wv >> 1) * 16, wn = (wv & 1) * 32;
  const u16* arow  = snb + (size_t)(m0 + wm + c16)*DMOD + c4*8;
  const u16* brow0 = wt + (size_t)(n0 + wn + c16)*DMOD + c4*8;
  const u16* brow1 = wt + (size_t)(n0 + wn + 16 + c16)*DMOD + c4*8;
  f32x4 acc0={0,0,0,0}, acc1={0,0,0,0};
  #pragma unroll 4
  for (int k0 = 0; k0 < DMOD; k0 += 32) {
    bf16x8 a  = *(const bf16x8*)(arow  + k0);
    bf16x8 b0 = *(const bf16x8*)(brow0 + k0);
    bf16x8 b1 = *(const bf16x8*)(brow1 + k0);
    acc0 = __builtin_amdgcn_mfma_f32_16x16x32_bf16(a,b0,acc0,0,0,0);
    acc1 = __builtin_amdgcn_mfma_f32_16x16x32_bf16(a,b1,acc1,0,0,0);
  }
  int r0 = c4*4;
  #pragma unroll
  for (int bn=0; bn<2; bn++) {
    f32x4 acc = bn==0?acc0:acc1;
    #pragma unroll
    for (int rr=0; rr<4; rr++) {
      int i = m0 + wm + r0 + rr;
      int n = n0 + wn + bn*16 + c16;
      float val = acc[rr];
      if (wsel == 0)      { val += qb[n]; qo[(size_t)i*DMOD + n] = f2bf(val); }
      else if (wsel == 1) { ko[(size_t)i*DMOD + n] = f2bf(val); }
      else if (wsel == 2) { vTo[(size_t)n*NTOK + i] = f2bf(val); }
      else                { go[(size_t)i*DMOD + n] = 1.f/(1.f + expf(-val)); }
    }
  }
}

static __device__ __forceinline__ void unit_attn(
    int u, int t, const u16* qo, const u16* ko, const u16* vTo,
    const u16* biasb, const float* go, u16* og, char* SM) {
  u16*   Pt  = (u16*)SM;
  float* OSp = (float*)(SM + 9216);
  float* LSp = (float*)(SM + 17664);
  int lane = t & 63, wv = t >> 6;
  int c16 = lane & 15, c4 = lane >> 4;
  int h  = u & 15;
  int i0 = (u >> 4) * 16;
  int r0 = c4 * 4;
  bf16x8 qf = *(const bf16x8*)(qo + (size_t)(i0 + c16)*DMOD + h*DH + c4*8);
  f32x4 o0 = {0,0,0,0}, o1 = {0,0,0,0};
  float ls[4] = {0.f,0.f,0.f,0.f};
  const float scale = 0.17677669529663687f;
  const u16* bbase = biasb + ((size_t)i0*NH + h)*NTOK;
  u16* pt = Pt + wv*(16*72);
  for (int jj = 0; jj < 3; jj++) {
    int j0 = wv*192 + jj*64;
    bf16x8 kf0 = *(const bf16x8*)(ko + (size_t)(j0 +  0 + c16)*DMOD + h*DH + c4*8);
    bf16x8 kf1 = *(const bf16x8*)(ko + (size_t)(j0 + 16 + c16)*DMOD + h*DH + c4*8);
    bf16x8 kf2 = *(const bf16x8*)(ko + (size_t)(j0 + 32 + c16)*DMOD + h*DH + c4*8);
    bf16x8 kf3 = *(const bf16x8*)(ko + (size_t)(j0 + 48 + c16)*DMOD + h*DH + c4*8);
    f32x4 zz = {0,0,0,0};
    f32x4 s0 = __builtin_amdgcn_mfma_f32_16x16x32_bf16(qf,kf0,zz,0,0,0);
    f32x4 s1 = __builtin_amdgcn_mfma_f32_16x16x32_bf16(qf,kf1,zz,0,0,0);
    f32x4 s2 = __builtin_amdgcn_mfma_f32_16x16x32_bf16(qf,kf2,zz,0,0,0);
    f32x4 s3 = __builtin_amdgcn_mfma_f32_16x16x32_bf16(qf,kf3,zz,0,0,0);
    #pragma unroll
    for (int rr=0; rr<4; rr++) {
      const u16* bp = bbase + (size_t)(r0+rr)*(NH*NTOK) + j0 + c16;
      int row = (r0 + rr) * 72;
      float p0 = __expf(s0[rr]*scale + bf2f(bp[ 0]));
      float p1 = __expf(s1[rr]*scale + bf2f(bp[16]));
      float p2 = __expf(s2[rr]*scale + bf2f(bp[32]));
      float p3 = __expf(s3[rr]*scale + bf2f(bp[48]));
      ls[rr] += p0 + p1 + p2 + p3;
      pt[row + 0*16 + c16] = f2bf(p0);
      pt[row + 1*16 + c16] = f2bf(p1);
      pt[row + 2*16 + c16] = f2bf(p2);
      pt[row + 3*16 + c16] = f2bf(p3);
    }
    #pragma unroll
    for (int ks=0; ks<2; ks++) {
      bf16x8 pf = *(const bf16x8*)(pt + c16*72 + ks*32 + c4*8);
      bf16x8 v0 = *(const bf16x8*)(vTo + (size_t)(h*DH + c16)*NTOK      + j0 + ks*32 + c4*8);
      bf16x8 v1 = *(const bf16x8*)(vTo + (size_t)(h*DH + 16 + c16)*NTOK + j0 + ks*32 + c4*8);
      o0 = __builtin_amdgcn_mfma_f32_16x16x32_bf16(pf, v0, o0, 0,0,0);
      o1 = __builtin_amdgcn_mfma_f32_16x16x32_bf16(pf, v1, o1, 0,0,0);
    }
  }
  #pragma unroll
  for (int rr=0; rr<4; rr++) {
    float l = ls[rr];
    l += __shfl_xor(l,1); l += __shfl_xor(l,2); l += __shfl_xor(l,4); l += __shfl_xor(l,8);
    OSp[(wv*16 + r0+rr)*33 + c16]      = o0[rr];
    OSp[(wv*16 + r0+rr)*33 + 16 + c16] = o1[rr];
    if (c16 == 0) LSp[wv*16 + r0+rr] = l;
  }
  __syncthreads();
  #pragma unroll
  for (int uu=0; uu<2; uu++) {
    int idx = t + uu*256;
    int row = idx >> 5, d = idx & 31;
    float osum = OSp[(0*16+row)*33 + d] + OSp[(1*16+row)*33 + d]
               + OSp[(2*16+row)*33 + d] + OSp[(3*16+row)*33 + d];
    float lsum = LSp[0*16+row] + LSp[1*16+row] + LSp[2*16+row] + LSp[3*16+row];
    int i = i0 + row;
    float g = go[(size_t)i*DMOD + h*DH + d];
    og[(size_t)i*DMOD + h*DH + d] = f2bf(osum/lsum*g);
  }
}

static __device__ __forceinline__ void unit_out(
    int u, int t, const u16* og, const u16* owT, float* outp) {
  int lane = t & 63, wv = t >> 6;
  int c16 = lane & 15, c4 = lane >> 4;
  int mb = u % 24, nbx = u / 24;
  int m0 = mb*32, n0 = nbx*64;
  int wm = (wv >> 1) * 16, wn = (wv & 1) * 32;
  const u16* arow  = og  + (size_t)(m0 + wm + c16)*DMOD + c4*8;
  const u16* brow0 = owT + (size_t)(n0 + wn + c16)*DMOD + c4*8;
  const u16* brow1 = owT + (size_t)(n0 + wn + 16 + c16)*DMOD + c4*8;
  f32x4 acc0={0,0,0,0}, acc1={0,0,0,0};
  #pragma unroll 4
  for (int k0 = 0; k0 < DMOD; k0 += 32) {
    bf16x8 a  = *(const bf16x8*)(arow  + k0);
    bf16x8 b0 = *(const bf16x8*)(brow0 + k0);
    bf16x8 b1 = *(const bf16x8*)(brow1 + k0);
    acc0 = __builtin_amdgcn_mfma_f32_16x16x32_bf16(a,b0,acc0,0,0,0);
    acc1 = __builtin_amdgcn_mfma_f32_16x16x32_bf16(a,b1,acc1,0,0,0);
  }
  int r0 = c4*4;
  #pragma unroll
  for (int bn=0; bn<2; bn++) {
    f32x4 acc = bn==0?acc0:acc1;
    #pragma unroll
    for (int rr=0; rr<4; rr++)
      outp[(size_t)(m0 + wm + r0 + rr)*DMOD + n0 + wn + bn*16 + c16] = acc[rr];
  }
}

// ===========================================================================
// Fused cooperative kernel: 512 blocks. NOTE: no second __launch_bounds__
// arg — (256,2) empirically capped VGPR at 64 (8 waves/EU) and spilled the
// whole z working set to scratch (r8/r9: 452/440 us, VALUBusy 5%).
// ===========================================================================
__global__ __launch_bounds__(256) void fused_kernel(
    const float* __restrict__ s, const float* __restrict__ nsw, const float* __restrict__ nsb,
    const float* __restrict__ qw, const float* __restrict__ kw, const float* __restrict__ vw,
    const float* __restrict__ gw, const float* __restrict__ ow,
    const float* __restrict__ z, const float* __restrict__ znw, const float* __restrict__ znb,
    const float* __restrict__ zwp, const float* __restrict__ qb,
    u16* __restrict__ wbf, u16* __restrict__ snb, u16* __restrict__ biasb,
    u16* __restrict__ qo, u16* __restrict__ ko, u16* __restrict__ vTo,
    float* __restrict__ go, u16* __restrict__ og, float* __restrict__ outp) {
  cg::grid_group grid = cg::this_grid();
  __shared__ __align__(16) char SM[18432];
  int t = threadIdx.x;
  int bid0 = blockIdx.x;
  const int NB = 512;
  int lane = t & 63, wv = t >> 6;
  int c16 = lane & 15, c4 = lane >> 4;

  // ---- P0: weight cvt (1280) + LN(s) (192) ----
  for (int u = bid0; u < 1472; u += NB) {
    if (u < 1280) unit_wcvt(u, t, qw, kw, vw, gw, ow, wbf, SM);
    else          unit_lns(u - 1280, t, s, nsw, nsb, snb);
    __syncthreads();
  }
  __threadfence();
  grid.sync();

  // ---- P1: z stream (18 units/block, prefetched) + qkvg tail ----
  {
    u16* zt = (u16*)SM;
    int rsub = t >> 5;
    int ch4  = (t & 31) * 4;
    bf16x8 bfr[4];
    #pragma unroll
    for (int ks=0; ks<4; ks++) {
      #pragma unroll
      for (int jj=0; jj<8; jj++)
        bfr[ks][jj] = (short)f2bf(zwp[(ks*32 + c4*8 + jj)*16 + c16]);
    }
    float4 w4 = *(const float4*)(znw + ch4);
    float4 b4 = *(const float4*)(znb + ch4);
    float4 xa[8], xb[8];
    int u0 = bid0;
    LOADZ(xa, u0)
    #pragma unroll 1
    for (int kk = 0; kk < 9; kk++) {
      int u1 = u0 + NB;
      LOADZ(xb, u1)
      PROCZ(xa, u0)
      if (kk < 8) { int u2 = u0 + 2*NB; LOADZ(xa, u2) }
      PROCZ(xb, u1)
      u0 += 2*NB;
    }
    for (int u = bid0 + 18*NB; u < 9984; u += NB)
      unit_qkvg(u - 9216, t, snb, wbf, qb, qo, ko, vTo, go);
  }
  __threadfence();
  grid.sync();

  // ---- P2: attention (768 units) ----
  for (int u = bid0; u < 768; u += NB) {
    unit_attn(u, t, qo, ko, vTo, biasb, go, og, SM);
    __syncthreads();
  }
  __threadfence();
  grid.sync();

  // ---- P3: out projection (192 units) ----
  for (int u = bid0; u < 192; u += NB)
    unit_out(u, t, og, wbf + (size_t)4*(DMOD*DMOD), outp);
}

// ===========================================================================
// Fallback kernels (round-6 verified structure)
// ===========================================================================
__global__ __launch_bounds__(256) void prep_kernel(
    const float* __restrict__ s, const float* __restrict__ nsw, const float* __restrict__ nsb,
    const float* __restrict__ qw, const float* __restrict__ kw, const float* __restrict__ vw,
    const float* __restrict__ gw, const float* __restrict__ ow,
    const float* __restrict__ z, const float* __restrict__ znw, const float* __restrict__ znb,
    const float* __restrict__ zwp,
    u16* __restrict__ wbf, u16* __restrict__ snb, u16* __restrict__ biasb) {
  __shared__ __align__(16) char SM[17408];
  int bid = blockIdx.x;
  int t = threadIdx.x;
  if (bid >= 9216) {
    if (bid < 10496) unit_wcvt(bid - 9216, t, qw, kw, vw, gw, ow, wbf, SM);
    else             unit_lns(bid - 10496, t, s, nsw, nsb, snb);
    return;
  }
  u16* zt = (u16*)SM;
  int lane = t & 63, wv = t >> 6;
  int c16 = lane & 15, c4 = lane >> 4;
  int rsub = t >> 5;
  int ch4  = (t & 31) * 4;
  bf16x8 bfr[4];
  #pragma unroll
  for (int ks=0; ks<4; ks++) {
    #pragma unroll
    for (int jj=0; jj<8; jj++)
      bfr[ks][jj] = (short)f2bf(zwp[(ks*32 + c4*8 + jj)*16 + c16]);
  }
  float4 w4 = *(const float4*)(znw + ch4);
  float4 b4 = *(const float4*)(znb + ch4);
  float4 xa[8];
  LOADZ(xa, bid)
  PROCZ(xa, bid)
}

__global__ __launch_bounds__(256) void qkvg_kernel(
    const u16* __restrict__ sn, const u16* __restrict__ wts, const float* __restrict__ qb,
    u16* __restrict__ qo, u16* __restrict__ ko, u16* __restrict__ vTo, float* __restrict__ go) {
  unit_qkvg(blockIdx.x, threadIdx.x, sn, wts, qb, qo, ko, vTo, go);
}

__global__ __launch_bounds__(256) void attn_kernel(
    const u16* __restrict__ qm, const u16* __restrict__ km, const u16* __restrict__ vTm,
    const u16* __restrict__ bias, const float* __restrict__ gm, u16* __restrict__ og) {
  __shared__ __align__(16) char SM[17920];
  unit_attn(blockIdx.x, threadIdx.x, qm, km, vTm, bias, gm, og, SM);
}

__global__ __launch_bounds__(256) void out_kernel(
    const u16* __restrict__ og, const u16* __restrict__ owT, float* __restrict__ out) {
  unit_out(blockIdx.x, threadIdx.x, og, owT, out);
}

// ---------------------------------------------------------------------------
extern "C" void kernel_launch(void* const* d_in, const int* in_sizes, int n_in,
                              void* d_out, int out_size, void* d_ws, size_t ws_size,
                              hipStream_t stream) {
  const float* s   = (const float*)d_in[0];
  const float* z   = (const float*)d_in[1];
  const float* nsw = (const float*)d_in[2];
  const float* nsb = (const float*)d_in[3];
  const float* qw  = (const float*)d_in[4];
  const float* qb  = (const float*)d_in[5];
  const float* kw  = (const float*)d_in[6];
  const float* vw  = (const float*)d_in[7];
  const float* gw  = (const float*)d_in[8];
  const float* znw = (const float*)d_in[9];
  const float* znb = (const float*)d_in[10];
  const float* zw  = (const float*)d_in[11];
  const float* ow  = (const float*)d_in[12];
  float* out = (float*)d_out;

  char* p = (char*)d_ws;
  u16* w_bf    = (u16*)p;  p += (size_t)5*DMOD*DMOD*2;
  u16* sn_bf   = (u16*)p;  p += (size_t)NTOK*DMOD*2;
  u16* q_bf    = (u16*)p;  p += (size_t)NTOK*DMOD*2;
  u16* k_bf    = (u16*)p;  p += (size_t)NTOK*DMOD*2;
  u16* vT_bf   = (u16*)p;  p += (size_t)NTOK*DMOD*2;
  float* g_f   = (float*)p; p += (size_t)NTOK*DMOD*4;
  u16* og_bf   = (u16*)p;  p += (size_t)NTOK*DMOD*2;
  u16* bias_bf = (u16*)p;  p += (size_t)NH*NN*2;

  void* args[] = { (void*)&s, (void*)&nsw, (void*)&nsb, (void*)&qw, (void*)&kw,
                   (void*)&vw, (void*)&gw, (void*)&ow, (void*)&z, (void*)&znw,
                   (void*)&znb, (void*)&zw, (void*)&qb,
                   (void*)&w_bf, (void*)&sn_bf, (void*)&bias_bf,
                   (void*)&q_bf, (void*)&k_bf, (void*)&vT_bf, (void*)&g_f,
                   (void*)&og_bf, (void*)&out };
  hipError_t cerr = hipLaunchCooperativeKernel((void*)fused_kernel, dim3(512), dim3(256),
                                               args, 0, stream);
  if (cerr != hipSuccess) {
    (void)hipGetLastError();   // clear sticky error, take the 4-kernel path
    prep_kernel<<<dim3(10688), dim3(256), 0, stream>>>(
        s, nsw, nsb, qw, kw, vw, gw, ow, z, znw, znb, zw, w_bf, sn_bf, bias_bf);
    qkvg_kernel<<<dim3(768), dim3(256), 0, stream>>>(sn_bf, w_bf, qb, q_bf, k_bf, vT_bf, g_f);
    attn_kernel<<<dim3(768), dim3(256), 0, stream>>>(q_bf, k_bf, vT_bf, bias_bf, g_f, og_bf);
    out_kernel<<<dim3(192), dim3(256), 0, stream>>>(og_bf, w_bf + (size_t)4*DMOD*DMOD, out);
  }
}

// Round 11
// 431.878 us; speedup vs baseline: 1.0481x; 1.0128x over previous
//
#include <hip/hip_runtime.h>
#include <hip/hip_bf16.h>
#include <hip/hip_cooperative_groups.h>

namespace cg = cooperative_groups;

typedef float f32x4 __attribute__((ext_vector_type(4)));
typedef short bf16x8 __attribute__((ext_vector_type(8)));
typedef unsigned short u16;

#define NTOK 768
#define DMOD 512
#define NH   16
#define DH   32
#define CZd  128
#define NN   (768*768)

static __device__ __forceinline__ u16 f2bf(float f) {
  __hip_bfloat16 h = __float2bfloat16(f);
  return __builtin_bit_cast(u16, h);
}
static __device__ __forceinline__ float bf2f(u16 u) {
  unsigned int x = ((unsigned int)u) << 16;
  return __builtin_bit_cast(float, x);
}

// ===========================================================================
// z-unit as macros (no function-boundary array passing). Context must
// provide: z, biasb, zt, rsub, ch4, wv, c16, c4, bfr[4], w4, b4.
// ===========================================================================
#define LOADZ(X, U) { \
  int zi_ = (U)/12, zj_ = ((U)%12)*64; \
  const float* zp_ = z + ((size_t)zi_*NTOK + zj_)*CZd; \
  _Pragma("unroll") \
  for (int it=0; it<8; it++) \
    X[it] = *(const float4*)(zp_ + (size_t)(it*8 + rsub)*CZd + ch4); \
}

#define PROCZ(X, U) { \
  float mu8_[8], rs8_[8]; \
  _Pragma("unroll") \
  for (int it=0; it<8; it++) { \
    float4 v_ = X[it]; \
    float sum_ = v_.x+v_.y+v_.z+v_.w; \
    float sq_  = v_.x*v_.x+v_.y*v_.y+v_.z*v_.z+v_.w*v_.w; \
    _Pragma("unroll") \
    for (int mk=1; mk<32; mk<<=1) { sum_ += __shfl_xor(sum_,mk); sq_ += __shfl_xor(sq_,mk); } \
    float mu_ = sum_*(1.f/128.f); \
    mu8_[it] = mu_; \
    rs8_[it] = rsqrtf(sq_*(1.f/128.f) - mu_*mu_ + 1e-5f); \
  } \
  _Pragma("unroll") \
  for (int it=0; it<8; it++) { \
    float4 v_ = X[it]; \
    float mu_ = mu8_[it], rs_ = rs8_[it]; \
    ushort4 o_; \
    o_.x = f2bf((v_.x-mu_)*rs_*w4.x + b4.x); \
    o_.y = f2bf((v_.y-mu_)*rs_*w4.y + b4.y); \
    o_.z = f2bf((v_.z-mu_)*rs_*w4.z + b4.z); \
    o_.w = f2bf((v_.w-mu_)*rs_*w4.w + b4.w); \
    *(ushort4*)(zt + (it*8 + rsub)*136 + ch4) = o_; \
  } \
  __syncthreads(); \
  f32x4 acc_ = {0,0,0,0}; \
  _Pragma("unroll") \
  for (int ks=0; ks<4; ks++) { \
    bf16x8 af_ = *(const bf16x8*)(zt + (wv*16 + c16)*136 + ks*32 + c4*8); \
    acc_ = __builtin_amdgcn_mfma_f32_16x16x32_bf16(af_, bfr[ks], acc_, 0,0,0); \
  } \
  { int zi_ = (U)/12, jl_ = ((U)%12)*64 + wv*16 + c4*4; \
    u16* bp_ = biasb + ((size_t)zi_*NH + c16)*NTOK + jl_; \
    ushort4 st_; \
    st_.x = f2bf(acc_[0]); st_.y = f2bf(acc_[1]); \
    st_.z = f2bf(acc_[2]); st_.w = f2bf(acc_[3]); \
    *(ushort4*)bp_ = st_; } \
  __syncthreads(); \
}

// ===========================================================================
// Simple unit bodies
// ===========================================================================
static __device__ __forceinline__ void unit_wcvt(
    int u, int t, const float* qw, const float* kw, const float* vw,
    const float* gw, const float* ow, u16* wbf, char* SM) {
  float (*tbuf)[33] = (float(*)[33])SM;
  int seg = u / 256, tile = u % 256;
  int k0 = (tile / 16) * 32, n0 = (tile % 16) * 32;
  const float* src = seg==0?qw: seg==1?kw: seg==2?vw: seg==3?gw: ow;
  u16* outw = wbf + (size_t)seg * (DMOD*DMOD);
  int tr  = t / 8, tc4 = (t % 8) * 4;
  float4 v = *(const float4*)(src + (size_t)(k0+tr)*DMOD + n0 + tc4);
  tbuf[tr][tc4+0]=v.x; tbuf[tr][tc4+1]=v.y; tbuf[tr][tc4+2]=v.z; tbuf[tr][tc4+3]=v.w;
  __syncthreads();
  int nr  = t / 8, kc4 = (t % 8) * 4;
  ushort4 o;
  o.x = f2bf(tbuf[kc4+0][nr]);
  o.y = f2bf(tbuf[kc4+1][nr]);
  o.z = f2bf(tbuf[kc4+2][nr]);
  o.w = f2bf(tbuf[kc4+3][nr]);
  *(ushort4*)(outw + (size_t)(n0+nr)*DMOD + k0 + kc4) = o;
}

static __device__ __forceinline__ void unit_lns(
    int u, int t, const float* s, const float* nsw, const float* nsb, u16* snb) {
  int i = u*4 + (t >> 6);
  int lane = t & 63;
  const float* row = s + (size_t)i*DMOD + lane*8;
  float4 a0 = *(const float4*)(row);
  float4 a1 = *(const float4*)(row + 4);
  float sum = a0.x+a0.y+a0.z+a0.w + a1.x+a1.y+a1.z+a1.w;
  float sq  = a0.x*a0.x+a0.y*a0.y+a0.z*a0.z+a0.w*a0.w
            + a1.x*a1.x+a1.y*a1.y+a1.z*a1.z+a1.w*a1.w;
  #pragma unroll
  for (int mk=1; mk<64; mk<<=1) { sum += __shfl_xor(sum,mk); sq += __shfl_xor(sq,mk); }
  float mu  = sum * (1.f/512.f);
  float var = sq  * (1.f/512.f) - mu*mu;
  float rs  = rsqrtf(var + 1e-5f);
  float4 w0 = *(const float4*)(nsw + lane*8);
  float4 w1 = *(const float4*)(nsw + lane*8 + 4);
  float4 b0 = *(const float4*)(nsb + lane*8);
  float4 b1 = *(const float4*)(nsb + lane*8 + 4);
  bf16x8 o;
  o[0]=(short)f2bf((a0.x-mu)*rs*w0.x+b0.x);
  o[1]=(short)f2bf((a0.y-mu)*rs*w0.y+b0.y);
  o[2]=(short)f2bf((a0.z-mu)*rs*w0.z+b0.z);
  o[3]=(short)f2bf((a0.w-mu)*rs*w0.w+b0.w);
  o[4]=(short)f2bf((a1.x-mu)*rs*w1.x+b1.x);
  o[5]=(short)f2bf((a1.y-mu)*rs*w1.y+b1.y);
  o[6]=(short)f2bf((a1.z-mu)*rs*w1.z+b1.z);
  o[7]=(short)f2bf((a1.w-mu)*rs*w1.w+b1.w);
  *(bf16x8*)(snb + (size_t)i*DMOD + lane*8) = o;
}

static __device__ __forceinline__ void unit_qkvg(
    int u2, int t, const u16* snb, const u16* wbf, const float* qb,
    u16* qo, u16* ko, u16* vTo, float* go) {
  int lane = t & 63, wv = t >> 6;
  int c16 = lane & 15, c4 = lane >> 4;
  int mb = u2 % 24, nbx = u2 / 24;
  int wsel = nbx >> 3, n0 = (nbx & 7) * 64, m0 = mb * 32;
  const u16* wt = wbf + (size_t)wsel * (DMOD*DMOD);
  int wm = (wv >> 1) * 16, wn = (wv & 1) * 32;
  const u16* arow  = snb + (size_t)(m0 + wm + c16)*DMOD + c4*8;
  const u16* brow0 = wt + (size_t)(n0 + wn + c16)*DMOD + c4*8;
  const u16* brow1 = wt + (size_t)(n0 + wn + 16 + c16)*DMOD + c4*8;
  f32x4 acc0={0,0,0,0}, acc1={0,0,0,0};
  #pragma unroll 4
  for (int k0 = 0; k0 < DMOD; k0 += 32) {
    bf16x8 a  = *(const bf16x8*)(arow  + k0);
    bf16x8 b0 = *(const bf16x8*)(brow0 + k0);
    bf16x8 b1 = *(const bf16x8*)(brow1 + k0);
    acc0 = __builtin_amdgcn_mfma_f32_16x16x32_bf16(a,b0,acc0,0,0,0);
    acc1 = __builtin_amdgcn_mfma_f32_16x16x32_bf16(a,b1,acc1,0,0,0);
  }
  int r0 = c4*4;
  #pragma unroll
  for (int bn=0; bn<2; bn++) {
    f32x4 acc = bn==0?acc0:acc1;
    #pragma unroll
    for (int rr=0; rr<4; rr++) {
      int i = m0 + wm + r0 + rr;
      int n = n0 + wn + bn*16 + c16;
      float val = acc[rr];
      if (wsel == 0)      { val += qb[n]; qo[(size_t)i*DMOD + n] = f2bf(val); }
      else if (wsel == 1) { ko[(size_t)i*DMOD + n] = f2bf(val); }
      else if (wsel == 2) { vTo[(size_t)n*NTOK + i] = f2bf(val); }
      else                { go[(size_t)i*DMOD + n] = 1.f/(1.f + expf(-val)); }
    }
  }
}

static __device__ __forceinline__ void unit_attn(
    int u, int t, const u16* qo, const u16* ko, const u16* vTo,
    const u16* biasb, const float* go, u16* og, char* SM) {
  u16*   Pt  = (u16*)SM;
  float* OSp = (float*)(SM + 9216);
  float* LSp = (float*)(SM + 17664);
  int lane = t & 63, wv = t >> 6;
  int c16 = lane & 15, c4 = lane >> 4;
  int h  = u & 15;
  int i0 = (u >> 4) * 16;
  int r0 = c4 * 4;
  bf16x8 qf = *(const bf16x8*)(qo + (size_t)(i0 + c16)*DMOD + h*DH + c4*8);
  f32x4 o0 = {0,0,0,0}, o1 = {0,0,0,0};
  float ls[4] = {0.f,0.f,0.f,0.f};
  const float scale = 0.17677669529663687f;
  const u16* bbase = biasb + ((size_t)i0*NH + h)*NTOK;
  u16* pt = Pt + wv*(16*72);
  for (int jj = 0; jj < 3; jj++) {
    int j0 = wv*192 + jj*64;
    bf16x8 kf0 = *(const bf16x8*)(ko + (size_t)(j0 +  0 + c16)*DMOD + h*DH + c4*8);
    bf16x8 kf1 = *(const bf16x8*)(ko + (size_t)(j0 + 16 + c16)*DMOD + h*DH + c4*8);
    bf16x8 kf2 = *(const bf16x8*)(ko + (size_t)(j0 + 32 + c16)*DMOD + h*DH + c4*8);
    bf16x8 kf3 = *(const bf16x8*)(ko + (size_t)(j0 + 48 + c16)*DMOD + h*DH + c4*8);
    f32x4 zz = {0,0,0,0};
    f32x4 s0 = __builtin_amdgcn_mfma_f32_16x16x32_bf16(qf,kf0,zz,0,0,0);
    f32x4 s1 = __builtin_amdgcn_mfma_f32_16x16x32_bf16(qf,kf1,zz,0,0,0);
    f32x4 s2 = __builtin_amdgcn_mfma_f32_16x16x32_bf16(qf,kf2,zz,0,0,0);
    f32x4 s3 = __builtin_amdgcn_mfma_f32_16x16x32_bf16(qf,kf3,zz,0,0,0);
    #pragma unroll
    for (int rr=0; rr<4; rr++) {
      const u16* bp = bbase + (size_t)(r0+rr)*(NH*NTOK) + j0 + c16;
      int row = (r0 + rr) * 72;
      float p0 = __expf(s0[rr]*scale + bf2f(bp[ 0]));
      float p1 = __expf(s1[rr]*scale + bf2f(bp[16]));
      float p2 = __expf(s2[rr]*scale + bf2f(bp[32]));
      float p3 = __expf(s3[rr]*scale + bf2f(bp[48]));
      ls[rr] += p0 + p1 + p2 + p3;
      pt[row + 0*16 + c16] = f2bf(p0);
      pt[row + 1*16 + c16] = f2bf(p1);
      pt[row + 2*16 + c16] = f2bf(p2);
      pt[row + 3*16 + c16] = f2bf(p3);
    }
    #pragma unroll
    for (int ks=0; ks<2; ks++) {
      bf16x8 pf = *(const bf16x8*)(pt + c16*72 + ks*32 + c4*8);
      bf16x8 v0 = *(const bf16x8*)(vTo + (size_t)(h*DH + c16)*NTOK      + j0 + ks*32 + c4*8);
      bf16x8 v1 = *(const bf16x8*)(vTo + (size_t)(h*DH + 16 + c16)*NTOK + j0 + ks*32 + c4*8);
      o0 = __builtin_amdgcn_mfma_f32_16x16x32_bf16(pf, v0, o0, 0,0,0);
      o1 = __builtin_amdgcn_mfma_f32_16x16x32_bf16(pf, v1, o1, 0,0,0);
    }
  }
  #pragma unroll
  for (int rr=0; rr<4; rr++) {
    float l = ls[rr];
    l += __shfl_xor(l,1); l += __shfl_xor(l,2); l += __shfl_xor(l,4); l += __shfl_xor(l,8);
    OSp[(wv*16 + r0+rr)*33 + c16]      = o0[rr];
    OSp[(wv*16 + r0+rr)*33 + 16 + c16] = o1[rr];
    if (c16 == 0) LSp[wv*16 + r0+rr] = l;
  }
  __syncthreads();
  #pragma unroll
  for (int uu=0; uu<2; uu++) {
    int idx = t + uu*256;
    int row = idx >> 5, d = idx & 31;
    float osum = OSp[(0*16+row)*33 + d] + OSp[(1*16+row)*33 + d]
               + OSp[(2*16+row)*33 + d] + OSp[(3*16+row)*33 + d];
    float lsum = LSp[0*16+row] + LSp[1*16+row] + LSp[2*16+row] + LSp[3*16+row];
    int i = i0 + row;
    float g = go[(size_t)i*DMOD + h*DH + d];
    og[(size_t)i*DMOD + h*DH + d] = f2bf(osum/lsum*g);
  }
}

static __device__ __forceinline__ void unit_out(
    int u, int t, const u16* og, const u16* owT, float* outp) {
  int lane = t & 63, wv = t >> 6;
  int c16 = lane & 15, c4 = lane >> 4;
  int mb = u % 24, nbx = u / 24;
  int m0 = mb*32, n0 = nbx*64;
  int wm = (wv >> 1) * 16, wn = (wv & 1) * 32;
  const u16* arow  = og  + (size_t)(m0 + wm + c16)*DMOD + c4*8;
  const u16* brow0 = owT + (size_t)(n0 + wn + c16)*DMOD + c4*8;
  const u16* brow1 = owT + (size_t)(n0 + wn + 16 + c16)*DMOD + c4*8;
  f32x4 acc0={0,0,0,0}, acc1={0,0,0,0};
  #pragma unroll 4
  for (int k0 = 0; k0 < DMOD; k0 += 32) {
    bf16x8 a  = *(const bf16x8*)(arow  + k0);
    bf16x8 b0 = *(const bf16x8*)(brow0 + k0);
    bf16x8 b1 = *(const bf16x8*)(brow1 + k0);
    acc0 = __builtin_amdgcn_mfma_f32_16x16x32_bf16(a,b0,acc0,0,0,0);
    acc1 = __builtin_amdgcn_mfma_f32_16x16x32_bf16(a,b1,acc1,0,0,0);
  }
  int r0 = c4*4;
  #pragma unroll
  for (int bn=0; bn<2; bn++) {
    f32x4 acc = bn==0?acc0:acc1;
    #pragma unroll
    for (int rr=0; rr<4; rr++)
      outp[(size_t)(m0 + wm + r0 + rr)*DMOD + n0 + wn + bn*16 + c16] = acc[rr];
  }
}

// ===========================================================================
// Fused cooperative kernel: 512 blocks. NOTE: no second __launch_bounds__
// arg — (256,2) empirically capped VGPR at 64 (8 waves/EU) and spilled the
// whole z working set to scratch (r8/r9: 452/440 us, VALUBusy 5%).
// ===========================================================================
__global__ __launch_bounds__(256) void fused_kernel(
    const float* __restrict__ s, const float* __restrict__ nsw, const float* __restrict__ nsb,
    const float* __restrict__ qw, const float* __restrict__ kw, const float* __restrict__ vw,
    const float* __restrict__ gw, const float* __restrict__ ow,
    const float* __restrict__ z, const float* __restrict__ znw, const float* __restrict__ znb,
    const float* __restrict__ zwp, const float* __restrict__ qb,
    u16* __restrict__ wbf, u16* __restrict__ snb, u16* __restrict__ biasb,
    u16* __restrict__ qo, u16* __restrict__ ko, u16* __restrict__ vTo,
    float* __restrict__ go, u16* __restrict__ og, float* __restrict__ outp) {
  cg::grid_group grid = cg::this_grid();
  __shared__ __align__(16) char SM[18432];
  int t = threadIdx.x;
  int bid0 = blockIdx.x;
  const int NB = 512;
  int lane = t & 63, wv = t >> 6;
  int c16 = lane & 15, c4 = lane >> 4;

  // ---- P0: weight cvt (1280) + LN(s) (192) ----
  for (int u = bid0; u < 1472; u += NB) {
    if (u < 1280) unit_wcvt(u, t, qw, kw, vw, gw, ow, wbf, SM);
    else          unit_lns(u - 1280, t, s, nsw, nsb, snb);
    __syncthreads();
  }
  __threadfence();
  grid.sync();

  // ---- P1: z stream (18 units/block, prefetched) + qkvg tail ----
  {
    u16* zt = (u16*)SM;
    int rsub = t >> 5;
    int ch4  = (t & 31) * 4;
    bf16x8 bfr[4];
    #pragma unroll
    for (int ks=0; ks<4; ks++) {
      #pragma unroll
      for (int jj=0; jj<8; jj++)
        bfr[ks][jj] = (short)f2bf(zwp[(ks*32 + c4*8 + jj)*16 + c16]);
    }
    float4 w4 = *(const float4*)(znw + ch4);
    float4 b4 = *(const float4*)(znb + ch4);
    float4 xa[8], xb[8];
    int u0 = bid0;
    LOADZ(xa, u0)
    #pragma unroll 1
    for (int kk = 0; kk < 9; kk++) {
      int u1 = u0 + NB;
      LOADZ(xb, u1)
      PROCZ(xa, u0)
      if (kk < 8) { int u2 = u0 + 2*NB; LOADZ(xa, u2) }
      PROCZ(xb, u1)
      u0 += 2*NB;
    }
    for (int u = bid0 + 18*NB; u < 9984; u += NB)
      unit_qkvg(u - 9216, t, snb, wbf, qb, qo, ko, vTo, go);
  }
  __threadfence();
  grid.sync();

  // ---- P2: attention (768 units) ----
  for (int u = bid0; u < 768; u += NB) {
    unit_attn(u, t, qo, ko, vTo, biasb, go, og, SM);
    __syncthreads();
  }
  __threadfence();
  grid.sync();

  // ---- P3: out projection (192 units) ----
  for (int u = bid0; u < 192; u += NB)
    unit_out(u, t, og, wbf + (size_t)4*(DMOD*DMOD), outp);
}

// ===========================================================================
// Fallback kernels (round-6 verified structure)
// ===========================================================================
__global__ __launch_bounds__(256) void prep_kernel(
    const float* __restrict__ s, const float* __restrict__ nsw, const float* __restrict__ nsb,
    const float* __restrict__ qw, const float* __restrict__ kw, const float* __restrict__ vw,
    const float* __restrict__ gw, const float* __restrict__ ow,
    const float* __restrict__ z, const float* __restrict__ znw, const float* __restrict__ znb,
    const float* __restrict__ zwp,
    u16* __restrict__ wbf, u16* __restrict__ snb, u16* __restrict__ biasb) {
  __shared__ __align__(16) char SM[17408];
  int bid = blockIdx.x;
  int t = threadIdx.x;
  if (bid >= 9216) {
    if (bid < 10496) unit_wcvt(bid - 9216, t, qw, kw, vw, gw, ow, wbf, SM);
    else             unit_lns(bid - 10496, t, s, nsw, nsb, snb);
    return;
  }
  u16* zt = (u16*)SM;
  int lane = t & 63, wv = t >> 6;
  int c16 = lane & 15, c4 = lane >> 4;
  int rsub = t >> 5;
  int ch4  = (t & 31) * 4;
  bf16x8 bfr[4];
  #pragma unroll
  for (int ks=0; ks<4; ks++) {
    #pragma unroll
    for (int jj=0; jj<8; jj++)
      bfr[ks][jj] = (short)f2bf(zwp[(ks*32 + c4*8 + jj)*16 + c16]);
  }
  float4 w4 = *(const float4*)(znw + ch4);
  float4 b4 = *(const float4*)(znb + ch4);
  float4 xa[8];
  LOADZ(xa, bid)
  PROCZ(xa, bid)
}

__global__ __launch_bounds__(256) void qkvg_kernel(
    const u16* __restrict__ sn, const u16* __restrict__ wts, const float* __restrict__ qb,
    u16* __restrict__ qo, u16* __restrict__ ko, u16* __restrict__ vTo, float* __restrict__ go) {
  unit_qkvg(blockIdx.x, threadIdx.x, sn, wts, qb, qo, ko, vTo, go);
}

__global__ __launch_bounds__(256) void attn_kernel(
    const u16* __restrict__ qm, const u16* __restrict__ km, const u16* __restrict__ vTm,
    const u16* __restrict__ bias, const float* __restrict__ gm, u16* __restrict__ og) {
  __shared__ __align__(16) char SM[17920];
  unit_attn(blockIdx.x, threadIdx.x, qm, km, vTm, bias, gm, og, SM);
}

__global__ __launch_bounds__(256) void out_kernel(
    const u16* __restrict__ og, const u16* __restrict__ owT, float* __restrict__ out) {
  unit_out(blockIdx.x, threadIdx.x, og, owT, out);
}

// ---------------------------------------------------------------------------
extern "C" void kernel_launch(void* const* d_in, const int* in_sizes, int n_in,
                              void* d_out, int out_size, void* d_ws, size_t ws_size,
                              hipStream_t stream) {
  const float* s   = (const float*)d_in[0];
  const float* z   = (const float*)d_in[1];
  const float* nsw = (const float*)d_in[2];
  const float* nsb = (const float*)d_in[3];
  const float* qw  = (const float*)d_in[4];
  const float* qb  = (const float*)d_in[5];
  const float* kw  = (const float*)d_in[6];
  const float* vw  = (const float*)d_in[7];
  const float* gw  = (const float*)d_in[8];
  const float* znw = (const float*)d_in[9];
  const float* znb = (const float*)d_in[10];
  const float* zw  = (const float*)d_in[11];
  const float* ow  = (const float*)d_in[12];
  float* out = (float*)d_out;

  char* p = (char*)d_ws;
  u16* w_bf    = (u16*)p;  p += (size_t)5*DMOD*DMOD*2;
  u16* sn_bf   = (u16*)p;  p += (size_t)NTOK*DMOD*2;
  u16* q_bf    = (u16*)p;  p += (size_t)NTOK*DMOD*2;
  u16* k_bf    = (u16*)p;  p += (size_t)NTOK*DMOD*2;
  u16* vT_bf   = (u16*)p;  p += (size_t)NTOK*DMOD*2;
  float* g_f   = (float*)p; p += (size_t)NTOK*DMOD*4;
  u16* og_bf   = (u16*)p;  p += (size_t)NTOK*DMOD*2;
  u16* bias_bf = (u16*)p;  p += (size_t)NH*NN*2;

  void* args[] = { (void*)&s, (void*)&nsw, (void*)&nsb, (void*)&qw, (void*)&kw,
                   (void*)&vw, (void*)&gw, (void*)&ow, (void*)&z, (void*)&znw,
                   (void*)&znb, (void*)&zw, (void*)&qb,
                   (void*)&w_bf, (void*)&sn_bf, (void*)&bias_bf,
                   (void*)&q_bf, (void*)&k_bf, (void*)&vT_bf, (void*)&g_f,
                   (void*)&og_bf, (void*)&out };
  hipError_t cerr = hipLaunchCooperativeKernel((void*)fused_kernel, dim3(512), dim3(256),
                                               args, 0, stream);
  if (cerr != hipSuccess) {
    (void)hipGetLastError();   // clear sticky error, take the 4-kernel path
    prep_kernel<<<dim3(10688), dim3(256), 0, stream>>>(
        s, nsw, nsb, qw, kw, vw, gw, ow, z, znw, znb, zw, w_bf, sn_bf, bias_bf);
    qkvg_kernel<<<dim3(768), dim3(256), 0, stream>>>(sn_bf, w_bf, qb, q_bf, k_bf, vT_bf, g_f);
    attn_kernel<<<dim3(768), dim3(256), 0, stream>>>(q_bf, k_bf, vT_bf, bias_bf, g_f, og_bf);
    out_kernel<<<dim3(192), dim3(256), 0, stream>>>(og_bf, w_bf + (size_t)4*DMOD*DMOD, out);
  }
}

// Round 12
// 102.423 us; speedup vs baseline: 4.4195x; 4.2166x over previous
//
#include <hip/hip_runtime.h>
#include <hip/hip_bf16.h>

typedef float f32x4 __attribute__((ext_vector_type(4)));
typedef short bf16x8 __attribute__((ext_vector_type(8)));
typedef unsigned short u16;

#define NTOK 768
#define DMOD 512
#define NH   16
#define DH   32
#define CZd  128
#define NN   (768*768)

static __device__ __forceinline__ u16 f2bf(float f) {
  __hip_bfloat16 h = __float2bfloat16(f);
  return __builtin_bit_cast(u16, h);
}
static __device__ __forceinline__ float bf2f(u16 u) {
  unsigned int x = ((unsigned int)u) << 16;
  return __builtin_bit_cast(float, x);
}

// ---------------------------------------------------------------------------
// K0 "prep": ONE launch; z-stream blocks first, cvt/LN in the tail.
//   blocks [0,4608)     : z path, TWO units per block (LDS double-buffer):
//                         LN(z) -> @z_w -> bias bf16 [i][h][j]
//   blocks [4608,5888)  : convert 5 weight mats f32 [k][n] -> bf16 [n][k]
//   blocks [5888,6080)  : LayerNorm(s) -> bf16, 4 rows per block
__global__ __launch_bounds__(256) void prep_kernel(
    const float* __restrict__ s, const float* __restrict__ nsw, const float* __restrict__ nsb,
    const float* __restrict__ qw, const float* __restrict__ kw, const float* __restrict__ vw,
    const float* __restrict__ gw, const float* __restrict__ ow,
    const float* __restrict__ z, const float* __restrict__ znw, const float* __restrict__ znb,
    const float* __restrict__ zwp,
    u16* __restrict__ wbf, u16* __restrict__ snb, u16* __restrict__ biasb) {
  __shared__ __align__(16) char SM[34816];       // 2 x 64 x 136 bf16
  int bid = blockIdx.x;
  int t = threadIdx.x;

  if (bid >= 4608) {
    if (bid < 5888) {          // ---- weight convert+transpose ----
      float (*tbuf)[33] = (float(*)[33])SM;
      int wb = bid - 4608;
      int seg = wb / 256;
      int tile = wb % 256;
      int k0 = (tile / 16) * 32;
      int n0 = (tile % 16) * 32;
      const float* src = seg==0?qw: seg==1?kw: seg==2?vw: seg==3?gw: ow;
      u16* outw = wbf + (size_t)seg * (DMOD*DMOD);
      int tr  = t / 8;
      int tc4 = (t % 8) * 4;
      float4 v = *(const float4*)(src + (size_t)(k0+tr)*DMOD + n0 + tc4);
      tbuf[tr][tc4+0]=v.x; tbuf[tr][tc4+1]=v.y; tbuf[tr][tc4+2]=v.z; tbuf[tr][tc4+3]=v.w;
      __syncthreads();
      int nr  = t / 8;
      int kc4 = (t % 8) * 4;
      ushort4 o;
      o.x = f2bf(tbuf[kc4+0][nr]);
      o.y = f2bf(tbuf[kc4+1][nr]);
      o.z = f2bf(tbuf[kc4+2][nr]);
      o.w = f2bf(tbuf[kc4+3][nr]);
      *(ushort4*)(outw + (size_t)(n0+nr)*DMOD + k0 + kc4) = o;
    } else {                   // ---- LayerNorm(s), 4 rows/block ----
      int i = (bid - 5888)*4 + (t >> 6);
      int lane = t & 63;
      const float* row = s + (size_t)i*DMOD + lane*8;
      float4 a0 = *(const float4*)(row);
      float4 a1 = *(const float4*)(row + 4);
      float sum = a0.x+a0.y+a0.z+a0.w + a1.x+a1.y+a1.z+a1.w;
      float sq  = a0.x*a0.x+a0.y*a0.y+a0.z*a0.z+a0.w*a0.w
                + a1.x*a1.x+a1.y*a1.y+a1.z*a1.z+a1.w*a1.w;
      #pragma unroll
      for (int mk=1; mk<64; mk<<=1) { sum += __shfl_xor(sum,mk); sq += __shfl_xor(sq,mk); }
      float mu  = sum * (1.f/512.f);
      float var = sq  * (1.f/512.f) - mu*mu;
      float rs  = rsqrtf(var + 1e-5f);
      float4 w0 = *(const float4*)(nsw + lane*8);
      float4 w1 = *(const float4*)(nsw + lane*8 + 4);
      float4 b0 = *(const float4*)(nsb + lane*8);
      float4 b1 = *(const float4*)(nsb + lane*8 + 4);
      bf16x8 o;
      o[0]=(short)f2bf((a0.x-mu)*rs*w0.x+b0.x);
      o[1]=(short)f2bf((a0.y-mu)*rs*w0.y+b0.y);
      o[2]=(short)f2bf((a0.z-mu)*rs*w0.z+b0.z);
      o[3]=(short)f2bf((a0.w-mu)*rs*w0.w+b0.w);
      o[4]=(short)f2bf((a1.x-mu)*rs*w1.x+b1.x);
      o[5]=(short)f2bf((a1.y-mu)*rs*w1.y+b1.y);
      o[6]=(short)f2bf((a1.z-mu)*rs*w1.z+b1.z);
      o[7]=(short)f2bf((a1.w-mu)*rs*w1.w+b1.w);
      *(bf16x8*)(snb + (size_t)i*DMOD + lane*8) = o;
    }
    return;
  }

  // ---- z path: units 2*bid and 2*bid+1 (same i, adjacent j0) ----
  u16* zt0 = (u16*)SM;               // 64 x 136 bf16
  u16* zt1 = (u16*)(SM + 17408);
  int u0 = bid * 2;
  int i  = u0 / 12;
  int j0 = (u0 % 12) * 64;           // unit A; unit B at j0+64
  int lane = t & 63, wv = t >> 6;
  int c16 = lane & 15, c4 = lane >> 4;
  int rsub = t >> 5;                 // 0..7
  int ch4  = (t & 31) * 4;           // 4 consecutive channels
  const float* ztA = z + ((size_t)i*NTOK + j0)*CZd;
  const float* ztB = ztA + (size_t)64*CZd;

  // ---- unit A loads (coalesced: lane*16B, 4KB per block step) ----
  float4 xv[8];
  #pragma unroll
  for (int it=0; it<8; it++)
    xv[it] = *(const float4*)(ztA + (size_t)(it*8 + rsub)*CZd + ch4);
  // hoisted constants (amortized over both units)
  bf16x8 bfr[4];
  #pragma unroll
  for (int ks=0; ks<4; ks++) {
    #pragma unroll
    for (int jj=0; jj<8; jj++)
      bfr[ks][jj] = (short)f2bf(zwp[(ks*32 + c4*8 + jj)*16 + c16]);
  }
  float4 w4 = *(const float4*)(znw + ch4);
  float4 b4 = *(const float4*)(znb + ch4);

  // ---- unit A: stats + normalize -> zt0 ----
  {
    float mu8[8], rs8[8];
    #pragma unroll
    for (int it=0; it<8; it++) {
      float4 v = xv[it];
      float sum = v.x+v.y+v.z+v.w;
      float sq  = v.x*v.x+v.y*v.y+v.z*v.z+v.w*v.w;
      #pragma unroll
      for (int mk=1; mk<32; mk<<=1) { sum += __shfl_xor(sum,mk); sq += __shfl_xor(sq,mk); }
      float mu = sum*(1.f/128.f);
      mu8[it] = mu;
      rs8[it] = rsqrtf(sq*(1.f/128.f) - mu*mu + 1e-5f);
    }
    #pragma unroll
    for (int it=0; it<8; it++) {
      float4 v = xv[it];
      float mu = mu8[it], rs = rs8[it];
      ushort4 o;
      o.x = f2bf((v.x-mu)*rs*w4.x + b4.x);
      o.y = f2bf((v.y-mu)*rs*w4.y + b4.y);
      o.z = f2bf((v.z-mu)*rs*w4.z + b4.z);
      o.w = f2bf((v.w-mu)*rs*w4.w + b4.w);
      *(ushort4*)(zt0 + (it*8 + rsub)*136 + ch4) = o;
    }
  }
  // ---- unit B loads issue here (xv regs now dead; overlap A's MFMA) ----
  float4 yv[8];
  #pragma unroll
  for (int it=0; it<8; it++)
    yv[it] = *(const float4*)(ztB + (size_t)(it*8 + rsub)*CZd + ch4);
  __syncthreads();                   // zt0 ready
  // ---- unit A: MFMA + bias store ----
  {
    f32x4 acc = {0,0,0,0};
    #pragma unroll
    for (int ks=0; ks<4; ks++) {
      bf16x8 af = *(const bf16x8*)(zt0 + (wv*16 + c16)*136 + ks*32 + c4*8);
      acc = __builtin_amdgcn_mfma_f32_16x16x32_bf16(af, bfr[ks], acc, 0,0,0);
    }
    int jl = j0 + wv*16 + c4*4;
    u16* bp = biasb + ((size_t)i*NH + c16)*NTOK + jl;
    ushort4 st;
    st.x = f2bf(acc[0]); st.y = f2bf(acc[1]); st.z = f2bf(acc[2]); st.w = f2bf(acc[3]);
    *(ushort4*)bp = st;
  }
  // ---- unit B: stats + normalize -> zt1 ----
  {
    float mu8[8], rs8[8];
    #pragma unroll
    for (int it=0; it<8; it++) {
      float4 v = yv[it];
      float sum = v.x+v.y+v.z+v.w;
      float sq  = v.x*v.x+v.y*v.y+v.z*v.z+v.w*v.w;
      #pragma unroll
      for (int mk=1; mk<32; mk<<=1) { sum += __shfl_xor(sum,mk); sq += __shfl_xor(sq,mk); }
      float mu = sum*(1.f/128.f);
      mu8[it] = mu;
      rs8[it] = rsqrtf(sq*(1.f/128.f) - mu*mu + 1e-5f);
    }
    #pragma unroll
    for (int it=0; it<8; it++) {
      float4 v = yv[it];
      float mu = mu8[it], rs = rs8[it];
      ushort4 o;
      o.x = f2bf((v.x-mu)*rs*w4.x + b4.x);
      o.y = f2bf((v.y-mu)*rs*w4.y + b4.y);
      o.z = f2bf((v.z-mu)*rs*w4.z + b4.z);
      o.w = f2bf((v.w-mu)*rs*w4.w + b4.w);
      *(ushort4*)(zt1 + (it*8 + rsub)*136 + ch4) = o;
    }
  }
  __syncthreads();                   // zt1 ready
  // ---- unit B: MFMA + bias store ----
  {
    f32x4 acc = {0,0,0,0};
    #pragma unroll
    for (int ks=0; ks<4; ks++) {
      bf16x8 af = *(const bf16x8*)(zt1 + (wv*16 + c16)*136 + ks*32 + c4*8);
      acc = __builtin_amdgcn_mfma_f32_16x16x32_bf16(af, bfr[ks], acc, 0,0,0);
    }
    int jl = j0 + 64 + wv*16 + c4*4;
    u16* bp = biasb + ((size_t)i*NH + c16)*NTOK + jl;
    ushort4 st;
    st.x = f2bf(acc[0]); st.y = f2bf(acc[1]); st.z = f2bf(acc[2]); st.w = f2bf(acc[3]);
    *(ushort4*)bp = st;
  }
}

// ---------------------------------------------------------------------------
// K2: fused Q/K/V/G projections, NO LDS (operands L2-resident), no barriers.
//     grid = 24 (M/32) * 32 (4 mats * 512/64) = 768 blocks of 256.
__global__ __launch_bounds__(256) void qkvg_kernel(
    const u16* __restrict__ sn, const u16* __restrict__ wts, const float* __restrict__ qb,
    u16* __restrict__ qo, u16* __restrict__ ko, u16* __restrict__ vTo, float* __restrict__ go) {
  int bid = blockIdx.x;
  int mb = bid % 24, nb = bid / 24;
  int wsel = nb >> 3, n0 = (nb & 7) * 64, m0 = mb * 32;
  const u16* wt = wts + (size_t)wsel * (DMOD*DMOD);
  int t = threadIdx.x, lane = t & 63, wv = t >> 6;
  int wm = (wv >> 1) * 16, wn = (wv & 1) * 32;
  int c16 = lane & 15, c4 = lane >> 4;
  const u16* arow  = sn + (size_t)(m0 + wm + c16)*DMOD + c4*8;
  const u16* brow0 = wt + (size_t)(n0 + wn + c16)*DMOD + c4*8;
  const u16* brow1 = wt + (size_t)(n0 + wn + 16 + c16)*DMOD + c4*8;
  f32x4 acc0={0,0,0,0}, acc1={0,0,0,0};
  #pragma unroll 4
  for (int k0 = 0; k0 < DMOD; k0 += 32) {
    bf16x8 a  = *(const bf16x8*)(arow  + k0);
    bf16x8 b0 = *(const bf16x8*)(brow0 + k0);
    bf16x8 b1 = *(const bf16x8*)(brow1 + k0);
    acc0 = __builtin_amdgcn_mfma_f32_16x16x32_bf16(a,b0,acc0,0,0,0);
    acc1 = __builtin_amdgcn_mfma_f32_16x16x32_bf16(a,b1,acc1,0,0,0);
  }
  int r0 = c4*4;
  #pragma unroll
  for (int bn=0; bn<2; bn++) {
    f32x4 acc = bn==0?acc0:acc1;
    #pragma unroll
    for (int rr=0; rr<4; rr++) {
      int i = m0 + wm + r0 + rr;
      int n = n0 + wn + bn*16 + c16;
      float val = acc[rr];
      if (wsel == 0)      { val += qb[n]; qo[(size_t)i*DMOD + n] = f2bf(val); }
      else if (wsel == 1) { ko[(size_t)i*DMOD + n] = f2bf(val); }
      else if (wsel == 2) { vTo[(size_t)n*NTOK + i] = f2bf(val); }
      else                { go[(size_t)i*DMOD + n] = 1.f/(1.f + expf(-val)); }
    }
  }
}

// ---------------------------------------------------------------------------
// K3: flash attention. Block = (head, 16-row i-tile), 4 waves split j 4 ways;
//     exact partial-sum combine (no max subtraction). Bias staged via b128
//     into wave-private LDS (r3-verified shape); K/V direct from global.
//     grid = 768 blocks of 256.
__global__ __launch_bounds__(256) void attn_kernel(
    const u16* __restrict__ qm, const u16* __restrict__ km, const u16* __restrict__ vTm,
    const u16* __restrict__ bias, const float* __restrict__ gm, u16* __restrict__ og) {
  __shared__ u16 Bt[4][16*72];
  __shared__ u16 Pt[4][16*72];
  __shared__ float OS[4][16][33];
  __shared__ float LS[4][16];
  int h  = blockIdx.x & 15;
  int i0 = (blockIdx.x >> 4) * 16;
  int t = threadIdx.x, lane = t & 63, wv = t >> 6;
  int c16 = lane & 15, c4 = lane >> 4, r0 = c4 * 4;
  bf16x8 qf = *(const bf16x8*)(qm + (size_t)(i0 + c16)*DMOD + h*DH + c4*8);
  f32x4 o0 = {0,0,0,0}, o1 = {0,0,0,0};
  float ls[4] = {0.f,0.f,0.f,0.f};
  const float scale = 0.17677669529663687f;  // 32^-0.5
  const u16* bbase = bias + ((size_t)i0*NH + h)*NTOK;   // [i][h][j], row stride NH*NTOK
  int br = lane >> 3;          // 0..7
  int bc = (lane & 7) * 8;     // 0..56
  u16* bt = &Bt[wv][0];
  u16* pt = &Pt[wv][0];
  for (int jj = 0; jj < 3; jj++) {
    int j0 = wv*192 + jj*64;
    bf16x8 bv0 = *(const bf16x8*)(bbase + (size_t)br*(NH*NTOK)     + j0 + bc);
    bf16x8 bv1 = *(const bf16x8*)(bbase + (size_t)(br+8)*(NH*NTOK) + j0 + bc);
    bf16x8 kf0 = *(const bf16x8*)(km + (size_t)(j0 +  0 + c16)*DMOD + h*DH + c4*8);
    bf16x8 kf1 = *(const bf16x8*)(km + (size_t)(j0 + 16 + c16)*DMOD + h*DH + c4*8);
    bf16x8 kf2 = *(const bf16x8*)(km + (size_t)(j0 + 32 + c16)*DMOD + h*DH + c4*8);
    bf16x8 kf3 = *(const bf16x8*)(km + (size_t)(j0 + 48 + c16)*DMOD + h*DH + c4*8);
    *(bf16x8*)(bt + br*72 + bc)     = bv0;
    *(bf16x8*)(bt + (br+8)*72 + bc) = bv1;
    f32x4 zz = {0,0,0,0};
    f32x4 s0 = __builtin_amdgcn_mfma_f32_16x16x32_bf16(qf,kf0,zz,0,0,0);
    f32x4 s1 = __builtin_amdgcn_mfma_f32_16x16x32_bf16(qf,kf1,zz,0,0,0);
    f32x4 s2 = __builtin_amdgcn_mfma_f32_16x16x32_bf16(qf,kf2,zz,0,0,0);
    f32x4 s3 = __builtin_amdgcn_mfma_f32_16x16x32_bf16(qf,kf3,zz,0,0,0);
    #pragma unroll
    for (int rr=0; rr<4; rr++) {
      int row = (r0 + rr) * 72;
      float p0 = __expf(s0[rr]*scale + bf2f(bt[row + 0*16 + c16]));
      float p1 = __expf(s1[rr]*scale + bf2f(bt[row + 1*16 + c16]));
      float p2 = __expf(s2[rr]*scale + bf2f(bt[row + 2*16 + c16]));
      float p3 = __expf(s3[rr]*scale + bf2f(bt[row + 3*16 + c16]));
      ls[rr] += p0 + p1 + p2 + p3;
      pt[row + 0*16 + c16] = f2bf(p0);
      pt[row + 1*16 + c16] = f2bf(p1);
      pt[row + 2*16 + c16] = f2bf(p2);
      pt[row + 3*16 + c16] = f2bf(p3);
    }
    #pragma unroll
    for (int ks=0; ks<2; ks++) {
      bf16x8 pf = *(const bf16x8*)(pt + c16*72 + ks*32 + c4*8);
      bf16x8 v0 = *(const bf16x8*)(vTm + (size_t)(h*DH + c16)*NTOK      + j0 + ks*32 + c4*8);
      bf16x8 v1 = *(const bf16x8*)(vTm + (size_t)(h*DH + 16 + c16)*NTOK + j0 + ks*32 + c4*8);
      o0 = __builtin_amdgcn_mfma_f32_16x16x32_bf16(pf, v0, o0, 0,0,0);
      o1 = __builtin_amdgcn_mfma_f32_16x16x32_bf16(pf, v1, o1, 0,0,0);
    }
  }
  #pragma unroll
  for (int rr=0; rr<4; rr++) {
    float l = ls[rr];
    l += __shfl_xor(l,1); l += __shfl_xor(l,2); l += __shfl_xor(l,4); l += __shfl_xor(l,8);
    OS[wv][r0+rr][c16]      = o0[rr];
    OS[wv][r0+rr][16 + c16] = o1[rr];
    if (c16 == 0) LS[wv][r0+rr] = l;
  }
  __syncthreads();
  #pragma unroll
  for (int u=0; u<2; u++) {
    int idx = t + u*256;
    int row = idx >> 5, d = idx & 31;
    float osum = OS[0][row][d] + OS[1][row][d] + OS[2][row][d] + OS[3][row][d];
    float lsum = LS[0][row] + LS[1][row] + LS[2][row] + LS[3][row];
    int i = i0 + row;
    float g = gm[(size_t)i*DMOD + h*DH + d];
    og[(size_t)i*DMOD + h*DH + d] = f2bf(osum/lsum*g);
  }
}

// ---------------------------------------------------------------------------
// K4: out = og @ o_w, NO LDS (both operands L2-resident), 32x64 tiles.
//     grid = 24*8 = 192 blocks of 256.
__global__ __launch_bounds__(256) void out_kernel(
    const u16* __restrict__ og, const u16* __restrict__ owT, float* __restrict__ out) {
  int bid = blockIdx.x;
  int mb = bid % 24, nb = bid / 24;
  int m0 = mb*32, n0 = nb*64;
  int t = threadIdx.x, lane = t & 63, wv = t >> 6;
  int wm = (wv >> 1) * 16, wn = (wv & 1) * 32;
  int c16 = lane & 15, c4 = lane >> 4;
  const u16* arow  = og  + (size_t)(m0 + wm + c16)*DMOD + c4*8;
  const u16* brow0 = owT + (size_t)(n0 + wn + c16)*DMOD + c4*8;
  const u16* brow1 = owT + (size_t)(n0 + wn + 16 + c16)*DMOD + c4*8;
  f32x4 acc0={0,0,0,0}, acc1={0,0,0,0};
  #pragma unroll 4
  for (int k0 = 0; k0 < DMOD; k0 += 32) {
    bf16x8 a  = *(const bf16x8*)(arow  + k0);
    bf16x8 b0 = *(const bf16x8*)(brow0 + k0);
    bf16x8 b1 = *(const bf16x8*)(brow1 + k0);
    acc0 = __builtin_amdgcn_mfma_f32_16x16x32_bf16(a,b0,acc0,0,0,0);
    acc1 = __builtin_amdgcn_mfma_f32_16x16x32_bf16(a,b1,acc1,0,0,0);
  }
  int r0 = c4*4;
  #pragma unroll
  for (int bn=0; bn<2; bn++) {
    f32x4 acc = bn==0?acc0:acc1;
    #pragma unroll
    for (int rr=0; rr<4; rr++)
      out[(size_t)(m0 + wm + r0 + rr)*DMOD + n0 + wn + bn*16 + c16] = acc[rr];
  }
}

// ---------------------------------------------------------------------------
extern "C" void kernel_launch(void* const* d_in, const int* in_sizes, int n_in,
                              void* d_out, int out_size, void* d_ws, size_t ws_size,
                              hipStream_t stream) {
  const float* s   = (const float*)d_in[0];
  const float* z   = (const float*)d_in[1];
  const float* nsw = (const float*)d_in[2];
  const float* nsb = (const float*)d_in[3];
  const float* qw  = (const float*)d_in[4];
  const float* qb  = (const float*)d_in[5];
  const float* kw  = (const float*)d_in[6];
  const float* vw  = (const float*)d_in[7];
  const float* gw  = (const float*)d_in[8];
  const float* znw = (const float*)d_in[9];
  const float* znb = (const float*)d_in[10];
  const float* zw  = (const float*)d_in[11];
  const float* ow  = (const float*)d_in[12];
  float* out = (float*)d_out;

  char* p = (char*)d_ws;
  u16* w_bf    = (u16*)p;  p += (size_t)5*DMOD*DMOD*2;
  u16* sn_bf   = (u16*)p;  p += (size_t)NTOK*DMOD*2;
  u16* q_bf    = (u16*)p;  p += (size_t)NTOK*DMOD*2;
  u16* k_bf    = (u16*)p;  p += (size_t)NTOK*DMOD*2;
  u16* vT_bf   = (u16*)p;  p += (size_t)NTOK*DMOD*2;
  float* g_f   = (float*)p; p += (size_t)NTOK*DMOD*4;
  u16* og_bf   = (u16*)p;  p += (size_t)NTOK*DMOD*2;
  u16* bias_bf = (u16*)p;  p += (size_t)NH*NN*2;

  prep_kernel<<<dim3(6080), dim3(256), 0, stream>>>(
      s, nsw, nsb, qw, kw, vw, gw, ow, z, znw, znb, zw, w_bf, sn_bf, bias_bf);
  qkvg_kernel<<<dim3(768), dim3(256), 0, stream>>>(sn_bf, w_bf, qb, q_bf, k_bf, vT_bf, g_f);
  attn_kernel<<<dim3(768), dim3(256), 0, stream>>>(q_bf, k_bf, vT_bf, bias_bf, g_f, og_bf);
  out_kernel<<<dim3(192), dim3(256), 0, stream>>>(og_bf, w_bf + (size_t)4*DMOD*DMOD, out);
}